// Round 1
// baseline (6308.710 us; speedup 1.0000x reference)
//
#include <hip/hip_runtime.h>
#include <cstdint>

#define SS 2048
#define HHd 512
#define FFd 2048
#define TTd 32
#define LLd 6

typedef float f32x4 __attribute__((ext_vector_type(4)));
typedef __bf16 bf16x8 __attribute__((ext_vector_type(8)));
typedef short short8v __attribute__((ext_vector_type(8)));
typedef short short4v __attribute__((ext_vector_type(4)));

__device__ __forceinline__ short f2b(float f) {
  unsigned u = __builtin_bit_cast(unsigned, f);
  u += 0x7fffu + ((u >> 16) & 1u);
  return (short)(u >> 16);
}

// ------------------------------ GEMM ------------------------------
// C[M,N] = A[M,K] @ B  (B is [K,N] if !TB, [N,K] if TB), A/B bf16, acc f32.
// Epilogue: v = acc*scale (+bias[col]) (+resid[row,col]) (ReLU) -> f32/bf16.
// blockIdx.z batching: B += (z/zdiv)*bs1 + (z%zdiv)*bs2, bias likewise, C += z*cStr.
#define BM 128
#define BN 128
#define KB 32
#define LDK 40

template<bool TB, bool BIAS, bool RELU, bool RESID, bool OUTF, bool OUTB>
__global__ __launch_bounds__(256) void gemm_k(
    const short* __restrict__ A, const short* __restrict__ Bb,
    const float* __restrict__ biasb, const float* __restrict__ resid,
    float* __restrict__ Cfb, short* __restrict__ Cbb,
    int M, int N, int K, float scale,
    int zdiv, long bs1, long bs2, int bb1, int bb2, long cStr)
{
  const int z = blockIdx.z;
  const short* B = Bb + (long)(z / zdiv) * bs1 + (long)(z % zdiv) * bs2;
  const float* bias = BIAS ? (biasb + (z / zdiv) * bb1 + (z % zdiv) * bb2) : nullptr;
  float* Cf = OUTF ? (Cfb + (long)z * cStr) : nullptr;
  short* Cb = OUTB ? (Cbb + (long)z * cStr) : nullptr;

  const int m0 = blockIdx.y * BM;
  const int n0 = blockIdx.x * BN;
  __shared__ __align__(16) short As[BM * LDK];
  __shared__ __align__(16) short Bs[BN * LDK];
  const int tid = threadIdx.x;
  const int lane = tid & 63;
  const int w = tid >> 6;
  const int wm = (w >> 1) * 64, wn = (w & 1) * 64;
  const int lrow = lane & 15, lk = (lane >> 4) * 8;

  f32x4 acc[4][4] = {};

  for (int k0 = 0; k0 < K; k0 += KB) {
#pragma unroll
    for (int it = 0; it < 2; ++it) {
      int idx = tid + it * 256;
      int r = idx >> 2, c = (idx & 3) * 8;
      *(int4*)&As[r * LDK + c] = *(const int4*)(A + (long)(m0 + r) * K + k0 + c);
    }
    if (TB) {
#pragma unroll
      for (int it = 0; it < 2; ++it) {
        int idx = tid + it * 256;
        int r = idx >> 2, c = (idx & 3) * 8;
        *(int4*)&Bs[r * LDK + c] = *(const int4*)(B + (long)(n0 + r) * K + k0 + c);
      }
    } else {
#pragma unroll
      for (int it = 0; it < 2; ++it) {
        int idx = tid + it * 256;
        int kk = idx >> 4, c = (idx & 15) * 8;
        short8v v = *(const short8v*)(B + (long)(k0 + kk) * N + n0 + c);
#pragma unroll
        for (int j = 0; j < 8; ++j) Bs[(c + j) * LDK + kk] = v[j];
      }
    }
    __syncthreads();
    bf16x8 af[4], bfv[4];
#pragma unroll
    for (int f = 0; f < 4; ++f) {
      af[f]  = *(const bf16x8*)&As[(wm + f * 16 + lrow) * LDK + lk];
      bfv[f] = *(const bf16x8*)&Bs[(wn + f * 16 + lrow) * LDK + lk];
    }
#pragma unroll
    for (int fm = 0; fm < 4; ++fm)
#pragma unroll
      for (int fn = 0; fn < 4; ++fn)
        acc[fm][fn] = __builtin_amdgcn_mfma_f32_16x16x32_bf16(af[fm], bfv[fn], acc[fm][fn], 0, 0, 0);
    __syncthreads();
  }

  const int crow = (lane >> 4) * 4;
  const int ccol = lane & 15;
#pragma unroll
  for (int fm = 0; fm < 4; ++fm) {
#pragma unroll
    for (int fn = 0; fn < 4; ++fn) {
      int gc = n0 + wn + fn * 16 + ccol;
      float bv = BIAS ? bias[gc] : 0.f;
#pragma unroll
      for (int r = 0; r < 4; ++r) {
        int gr = m0 + wm + fm * 16 + crow + r;
        long off = (long)gr * N + gc;
        float v = acc[fm][fn][r] * scale + bv;
        if (RESID) v += resid[off];
        if (RELU) v = v > 0.f ? v : 0.f;
        if (OUTF) Cf[off] = v;
        if (OUTB) Cb[off] = f2b(v);
      }
    }
  }
}

// ------------------------------ softmax over rows of [SS,SS] ------------------------------
__global__ __launch_bounds__(256) void softmax_k(const float* __restrict__ Sc, short* __restrict__ P) {
  const int row = blockIdx.x;
  const float* src = Sc + (long)row * SS;
  const int tid = threadIdx.x;
  float vals[8];
  float mx = -3.0e38f;
#pragma unroll
  for (int i = 0; i < 8; ++i) {
    vals[i] = src[tid + i * 256];
    mx = fmaxf(mx, vals[i]);
  }
#pragma unroll
  for (int o = 32; o; o >>= 1) mx = fmaxf(mx, __shfl_xor(mx, o));
  __shared__ float r1[4], r2[4];
  if ((tid & 63) == 0) r1[tid >> 6] = mx;
  __syncthreads();
  mx = fmaxf(fmaxf(r1[0], r1[1]), fmaxf(r1[2], r1[3]));
  float sum = 0.f;
#pragma unroll
  for (int i = 0; i < 8; ++i) { vals[i] = __expf(vals[i] - mx); sum += vals[i]; }
#pragma unroll
  for (int o = 32; o; o >>= 1) sum += __shfl_xor(sum, o);
  if ((tid & 63) == 0) r2[tid >> 6] = sum;
  __syncthreads();
  sum = r2[0] + r2[1] + r2[2] + r2[3];
  float inv = 1.0f / sum;
  short* dst = P + (long)row * SS;
#pragma unroll
  for (int i = 0; i < 8; ++i) dst[tid + i * 256] = f2b(vals[i] * inv);
}

// ------------------------------ LayerNorm over rows of [SS,HHd] ------------------------------
__global__ __launch_bounds__(256) void ln_k(const float* __restrict__ X, const float* __restrict__ w,
                                            const float* __restrict__ b, float* __restrict__ Yf,
                                            short* __restrict__ Yb) {
  const int row = blockIdx.x;
  const int tid = threadIdx.x;
  const float* src = X + (long)row * HHd;
  float x0 = src[tid], x1 = src[tid + 256];
  float s = x0 + x1;
#pragma unroll
  for (int o = 32; o; o >>= 1) s += __shfl_xor(s, o);
  __shared__ float r1[4], r2[4];
  if ((tid & 63) == 0) r1[tid >> 6] = s;
  __syncthreads();
  float mean = (r1[0] + r1[1] + r1[2] + r1[3]) * (1.f / HHd);
  float d0 = x0 - mean, d1 = x1 - mean;
  float q = d0 * d0 + d1 * d1;
#pragma unroll
  for (int o = 32; o; o >>= 1) q += __shfl_xor(q, o);
  if ((tid & 63) == 0) r2[tid >> 6] = q;
  __syncthreads();
  float var = (r2[0] + r2[1] + r2[2] + r2[3]) * (1.f / HHd);
  float rs = rsqrtf(var + 1e-5f);
  float o0 = d0 * rs * w[tid] + b[tid];
  float o1 = d1 * rs * w[tid + 256] + b[tid + 256];
  long base = (long)row * HHd;
  Yf[base + tid] = o0; Yf[base + tid + 256] = o1;
  Yb[base + tid] = f2b(o0); Yb[base + tid + 256] = f2b(o1);
}

// ------------------------------ embedding gather ------------------------------
__global__ __launch_bounds__(256) void gather_k(const int* __restrict__ sent, const float* __restrict__ emb,
                                                float* __restrict__ hf, short* __restrict__ hb,
                                                float* __restrict__ yf, short* __restrict__ yb) {
  long i = (long)blockIdx.x * 256 + threadIdx.x;
  int s = (int)(i >> 9);
  int hcol = (int)(i & 511);
  float v = emb[(long)sent[s] * HHd + hcol];
  short bb = f2b(v);
  hf[i] = v; yf[i] = v; hb[i] = bb; yb[i] = bb;
}

// ------------------------------ f32 -> bf16 convert ------------------------------
__global__ __launch_bounds__(256) void cvt_k(const float* __restrict__ x, short* __restrict__ y, long n) {
  long i = ((long)blockIdx.x * 256 + threadIdx.x) * 4;
  if (i >= n) return;
  float4 v = *(const float4*)(x + i);
  short4v o;
  o[0] = f2b(v.x); o[1] = f2b(v.y); o[2] = f2b(v.z); o[3] = f2b(v.w);
  *(short4v*)(y + i) = o;
}

// ------------------------------ feats: [SS,HHd] @ [HHd,TTd] + b (f32) ------------------------------
__global__ __launch_bounds__(256) void feats_k(const float* __restrict__ Y, const float* __restrict__ W,
                                               const float* __restrict__ b, float* __restrict__ feats) {
  __shared__ float ys[8 * HHd];
  const int row0 = blockIdx.x * 8;
  for (int i = threadIdx.x; i < 8 * HHd; i += 256) ys[i] = Y[(long)row0 * HHd + i];
  __syncthreads();
  const int n = threadIdx.x & 31, r = threadIdx.x >> 5;
  float acc = b[n];
  const float* yr = &ys[r * HHd];
  for (int k = 0; k < HHd; ++k) acc = fmaf(yr[k], W[k * TTd + n], acc);
  feats[(long)(row0 + r) * TTd + n] = acc;
}

// ------------------------------ Viterbi (single block, 64 threads) ------------------------------
__global__ __launch_bounds__(64) void viterbi_k(const float* __restrict__ feats,
                                                const float* __restrict__ trans,
                                                float* __restrict__ out,
                                                unsigned char* __restrict__ bpg) {
  __shared__ float fbuf[64 * 32];
  __shared__ float fvS[32];
  __shared__ unsigned char GsL[64 * 32];
  __shared__ unsigned char bnd[64];
  const int lane = threadIdx.x;
  const int nx = lane >> 1;  // next tag
  const int h = lane & 1;    // prev half
  float tr[16];
#pragma unroll
  for (int j = 0; j < 16; ++j) tr[j] = trans[nx * 32 + 16 * h + j];
  // fvreg: lane<32 holds fv[lane]
  float fvreg = (lane == 30) ? 0.f : -10000.f;

  for (int t = 0; t < 2048; ++t) {
    if ((t & 63) == 0) {
      for (int i = lane; i < 2048; i += 64) fbuf[i] = feats[(long)t * 32 + i];
      __syncthreads();
    }
    float best; int bi;
    {
      int p0 = 16 * h;
      float fvp = __shfl(fvreg, p0);
      best = fvp + tr[0]; bi = p0;
#pragma unroll
      for (int j = 1; j < 16; ++j) {
        int p = p0 + j;
        float v = __shfl(fvreg, p) + tr[j];
        if (v > best) { best = v; bi = p; }
      }
    }
    float ob = __shfl_xor(best, 1);
    int obi = __shfl_xor(bi, 1);
    float b0 = h ? ob : best, b1 = h ? best : ob;
    int i0 = h ? obi : bi, i1 = h ? bi : obi;
    bool take1 = b1 > b0;
    float m = take1 ? b1 : b0;
    int mi = take1 ? i1 : i0;
    float nf = m + fbuf[(t & 63) * 32 + nx];
    if (!h) bpg[t * 32 + nx] = (unsigned char)mi;
    // redistribute new fv to lanes 0..31
    fvreg = __shfl(nf, 2 * lane);  // lanes>=32 get garbage, never sourced
  }
  if (lane < 32) fvS[lane] = fvreg;
  __threadfence();
  __syncthreads();

  // chunk map composition: lane c composes bp rows [32c .. 32c+31]
  const int c = lane;
  unsigned char g[32];
#pragma unroll
  for (int j = 0; j < 32; ++j) g[j] = (unsigned char)j;
  for (int sIdx = 31; sIdx >= 0; --sIdx) {
    const unsigned char* rowp = bpg + (c * 32 + sIdx) * 32;
#pragma unroll
    for (int j = 0; j < 32; ++j) g[j] = rowp[g[j]];
  }
#pragma unroll
  for (int j = 0; j < 32; ++j) GsL[c * 32 + j] = g[j];
  __syncthreads();

  if (lane == 0) {
    float best = -3.0e38f; int bt = 0;
    for (int j = 0; j < 32; ++j) {
      float v = fvS[j] + trans[31 * 32 + j];
      if (v > best) { best = v; bt = j; }
    }
    out[0] = best;
    bnd[63] = (unsigned char)bt;
    for (int cc = 63; cc >= 1; --cc) bnd[cc - 1] = GsL[cc * 32 + bnd[cc]];
  }
  __syncthreads();

  int x = bnd[c];
  out[1 + c * 32 + 31] = (float)x;
  for (int k = 30; k >= 0; --k) {
    x = bpg[(c * 32 + k + 1) * 32 + x];
    out[1 + c * 32 + k] = (float)x;
  }
}

// ------------------------------ host ------------------------------
extern "C" void kernel_launch(void* const* d_in, const int* in_sizes, int n_in,
                              void* d_out, int out_size, void* d_ws, size_t ws_size,
                              hipStream_t stream) {
  (void)in_sizes; (void)n_in; (void)out_size; (void)ws_size;
  const int H = HHd, F = FFd, S = SS, L = LLd;
  const long HH2 = (long)H * H;   // 262144
  const long SH = (long)S * H;    // 1048576
  const long HF = (long)H * F;

  const int*   sent = (const int*)d_in[0];
  const float* embd = (const float*)d_in[1];
  const float* eaw  = (const float*)d_in[2];
  const float* eab  = (const float*)d_in[3];
  const float* ew1  = (const float*)d_in[4];
  const float* eb1  = (const float*)d_in[5];
  const float* ew2  = (const float*)d_in[6];
  const float* eb2  = (const float*)d_in[7];
  const float* elnw = (const float*)d_in[8];
  const float* elnb = (const float*)d_in[9];
  const float* daw  = (const float*)d_in[10];
  const float* dab  = (const float*)d_in[11];
  const float* dw1  = (const float*)d_in[12];
  const float* db1  = (const float*)d_in[13];
  const float* dw2  = (const float*)d_in[14];
  const float* db2  = (const float*)d_in[15];
  const float* dlnw = (const float*)d_in[16];
  const float* dlnb = (const float*)d_in[17];
  const float* enw  = (const float*)d_in[18];
  const float* enb  = (const float*)d_in[19];
  const float* dnw  = (const float*)d_in[20];
  const float* dnb  = (const float*)d_in[21];
  const float* h2tw = (const float*)d_in[22];
  const float* h2tb = (const float*)d_in[23];
  const float* trns = (const float*)d_in[24];

  char* p = (char*)d_ws;
  auto alloc = [&](size_t bytes) -> char* {
    char* r = p;
    p += (bytes + 255) & ~(size_t)255;
    return r;
  };
  short* wEA  = (short*)alloc((size_t)L * 4 * HH2 * 2);
  short* wE1  = (short*)alloc((size_t)L * HF * 2);
  short* wE2  = (short*)alloc((size_t)L * HF * 2);
  short* wDA  = (short*)alloc((size_t)L * 8 * HH2 * 2);
  short* wD1  = (short*)alloc((size_t)L * HF * 2);
  short* wD2  = (short*)alloc((size_t)L * HF * 2);
  float* h_f  = (float*)alloc(SH * 4);
  short* h_b  = (short*)alloc(SH * 2);
  float* y_f  = (float*)alloc(SH * 4);
  short* y_b  = (short*)alloc(SH * 2);
  float* tmpf = (float*)alloc(SH * 4);
  short* qkvb = (short*)alloc(3 * SH * 2);
  float* scf  = (float*)alloc((size_t)S * S * 4);
  short* P_b  = (short*)alloc((size_t)S * S * 2);
  short* attb = (short*)alloc(SH * 2);
  short* ff1b = (short*)alloc((size_t)S * F * 2);
  short* memb = (short*)alloc(SH * 2);
  short* ckvb = (short*)alloc((size_t)12 * SH * 2);
  float* yfin = (float*)alloc(SH * 4);
  float* ftsf = (float*)alloc((size_t)S * TTd * 4);
  unsigned char* bpg = (unsigned char*)alloc((size_t)2048 * 32);

  const int ZBIG = 1 << 20;
  const float RSQ = 0.04419417382415922f;  // 1/sqrt(512)

  auto cvt = [&](const float* src, short* dst, long n) {
    cvt_k<<<dim3((unsigned)((n / 4 + 255) / 256)), 256, 0, stream>>>(src, dst, n);
  };
  cvt(eaw, wEA, (long)L * 4 * HH2);
  cvt(ew1, wE1, (long)L * HF);
  cvt(ew2, wE2, (long)L * HF);
  cvt(daw, wDA, (long)L * 8 * HH2);
  cvt(dw1, wD1, (long)L * HF);
  cvt(dw2, wD2, (long)L * HF);

  gather_k<<<dim3((unsigned)(SH / 256)), 256, 0, stream>>>(sent, embd, h_f, h_b, y_f, y_b);

  dim3 gN512(4, 16, 1), gN2048(16, 16, 1);

  // ---------------- encoder ----------------
  for (int i = 0; i < L; ++i) {
    // qkv (batched z=0..2)
    gemm_k<false, true, false, false, false, true><<<dim3(4, 16, 3), 256, 0, stream>>>(
        h_b, wEA + (size_t)i * 4 * HH2, eab + (size_t)i * 4 * H, nullptr, nullptr, qkvb,
        S, H, H, 1.f, ZBIG, 0, HH2, 0, H, SH);
    // scores = q @ k^T * rsq
    gemm_k<true, false, false, false, true, false><<<gN2048, 256, 0, stream>>>(
        qkvb, qkvb + SH, nullptr, nullptr, scf, nullptr,
        S, S, H, RSQ, 1, 0, 0, 0, 0, 0);
    softmax_k<<<dim3(S), 256, 0, stream>>>(scf, P_b);
    // attn = P @ v
    gemm_k<false, false, false, false, false, true><<<gN512, 256, 0, stream>>>(
        P_b, qkvb + 2 * SH, nullptr, nullptr, nullptr, attb,
        S, H, S, 1.f, 1, 0, 0, 0, 0, 0);
    // out proj + residual
    gemm_k<false, true, false, true, true, false><<<gN512, 256, 0, stream>>>(
        attb, wEA + ((size_t)i * 4 + 3) * HH2, eab + ((size_t)i * 4 + 3) * H, h_f, tmpf, nullptr,
        S, H, H, 1.f, 1, 0, 0, 0, 0, 0);
    ln_k<<<dim3(S), 256, 0, stream>>>(tmpf, elnw + (size_t)(i * 2) * H, elnb + (size_t)(i * 2) * H, h_f, h_b);
    // FFN
    gemm_k<false, true, true, false, false, true><<<gN2048, 256, 0, stream>>>(
        h_b, wE1 + (size_t)i * HF, eb1 + (size_t)i * F, nullptr, nullptr, ff1b,
        S, F, H, 1.f, 1, 0, 0, 0, 0, 0);
    gemm_k<false, true, false, true, true, false><<<gN512, 256, 0, stream>>>(
        ff1b, wE2 + (size_t)i * HF, eb2 + (size_t)i * H, h_f, tmpf, nullptr,
        S, H, F, 1.f, 1, 0, 0, 0, 0, 0);
    ln_k<<<dim3(S), 256, 0, stream>>>(tmpf, elnw + (size_t)(i * 2 + 1) * H, elnb + (size_t)(i * 2 + 1) * H, h_f, h_b);
  }
  // mem = LN(h)
  ln_k<<<dim3(S), 256, 0, stream>>>(h_f, enw, enb, tmpf, memb);

  // cross K/V for all layers (z=0..11; z=2*layer+{0:k,1:v}), weights j=5,6
  gemm_k<false, true, false, false, false, true><<<dim3(4, 16, 12), 256, 0, stream>>>(
      memb, wDA + 5 * HH2, dab + 5 * H, nullptr, nullptr, ckvb,
      S, H, H, 1.f, 2, 8 * HH2, HH2, 8 * H, H, SH);

  // ---------------- decoder ----------------
  for (int i = 0; i < L; ++i) {
    // self-attn qkv
    gemm_k<false, true, false, false, false, true><<<dim3(4, 16, 3), 256, 0, stream>>>(
        y_b, wDA + (size_t)i * 8 * HH2, dab + (size_t)i * 8 * H, nullptr, nullptr, qkvb,
        S, H, H, 1.f, ZBIG, 0, HH2, 0, H, SH);
    gemm_k<true, false, false, false, true, false><<<gN2048, 256, 0, stream>>>(
        qkvb, qkvb + SH, nullptr, nullptr, scf, nullptr,
        S, S, H, RSQ, 1, 0, 0, 0, 0, 0);
    softmax_k<<<dim3(S), 256, 0, stream>>>(scf, P_b);
    gemm_k<false, false, false, false, false, true><<<gN512, 256, 0, stream>>>(
        P_b, qkvb + 2 * SH, nullptr, nullptr, nullptr, attb,
        S, H, S, 1.f, 1, 0, 0, 0, 0, 0);
    gemm_k<false, true, false, true, true, false><<<gN512, 256, 0, stream>>>(
        attb, wDA + ((size_t)i * 8 + 3) * HH2, dab + ((size_t)i * 8 + 3) * H, y_f, tmpf, nullptr,
        S, H, H, 1.f, 1, 0, 0, 0, 0, 0);
    ln_k<<<dim3(S), 256, 0, stream>>>(tmpf, dlnw + (size_t)(i * 3) * H, dlnb + (size_t)(i * 3) * H, y_f, y_b);
    // cross-attn: q from y
    gemm_k<false, true, false, false, false, true><<<gN512, 256, 0, stream>>>(
        y_b, wDA + ((size_t)i * 8 + 4) * HH2, dab + ((size_t)i * 8 + 4) * H, nullptr, nullptr, qkvb,
        S, H, H, 1.f, 1, 0, 0, 0, 0, 0);
    gemm_k<true, false, false, false, true, false><<<gN2048, 256, 0, stream>>>(
        qkvb, ckvb + (size_t)(2 * i) * SH, nullptr, nullptr, scf, nullptr,
        S, S, H, RSQ, 1, 0, 0, 0, 0, 0);
    softmax_k<<<dim3(S), 256, 0, stream>>>(scf, P_b);
    gemm_k<false, false, false, false, false, true><<<gN512, 256, 0, stream>>>(
        P_b, ckvb + (size_t)(2 * i + 1) * SH, nullptr, nullptr, nullptr, attb,
        S, H, S, 1.f, 1, 0, 0, 0, 0, 0);
    gemm_k<false, true, false, true, true, false><<<gN512, 256, 0, stream>>>(
        attb, wDA + ((size_t)i * 8 + 7) * HH2, dab + ((size_t)i * 8 + 7) * H, y_f, tmpf, nullptr,
        S, H, H, 1.f, 1, 0, 0, 0, 0, 0);
    ln_k<<<dim3(S), 256, 0, stream>>>(tmpf, dlnw + (size_t)(i * 3 + 1) * H, dlnb + (size_t)(i * 3 + 1) * H, y_f, y_b);
    // FFN
    gemm_k<false, true, true, false, false, true><<<gN2048, 256, 0, stream>>>(
        y_b, wD1 + (size_t)i * HF, db1 + (size_t)i * F, nullptr, nullptr, ff1b,
        S, F, H, 1.f, 1, 0, 0, 0, 0, 0);
    gemm_k<false, true, false, true, true, false><<<gN512, 256, 0, stream>>>(
        ff1b, wD2 + (size_t)i * HF, db2 + (size_t)i * H, y_f, tmpf, nullptr,
        S, H, F, 1.f, 1, 0, 0, 0, 0, 0);
    ln_k<<<dim3(S), 256, 0, stream>>>(tmpf, dlnw + (size_t)(i * 3 + 2) * H, dlnb + (size_t)(i * 3 + 2) * H, y_f, y_b);
  }
  // final norm + feats + viterbi
  ln_k<<<dim3(S), 256, 0, stream>>>(y_f, dnw, dnb, yfin, memb);
  feats_k<<<dim3(S / 8), 256, 0, stream>>>(yfin, h2tw, h2tb, ftsf);
  viterbi_k<<<dim3(1), 64, 0, stream>>>(ftsf, trns, (float*)d_out, bpg);
}

// Round 2
// 3299.773 us; speedup vs baseline: 1.9119x; 1.9119x over previous
//
#include <hip/hip_runtime.h>
#include <cstdint>

#define SS 2048
#define HHd 512
#define FFd 2048
#define TTd 32
#define LLd 6

typedef float f32x4 __attribute__((ext_vector_type(4)));
typedef __bf16 bf16x8 __attribute__((ext_vector_type(8)));
typedef short short8v __attribute__((ext_vector_type(8)));
typedef short short4v __attribute__((ext_vector_type(4)));

__device__ __forceinline__ short f2b(float f) {
  unsigned u = __builtin_bit_cast(unsigned, f);
  u += 0x7fffu + ((u >> 16) & 1u);
  return (short)(u >> 16);
}

typedef const __attribute__((address_space(1))) void gv_t;
typedef __attribute__((address_space(3))) void lv_t;
__device__ __forceinline__ void gload16(const void* g, void* l) {
  __builtin_amdgcn_global_load_lds((gv_t*)g, (lv_t*)l, 16, 0, 0);
}

// ------------------------------ GEMM (all-TB, m97 structure) ------------------------------
// C[M,N] = A[M,K] @ B^T where B is [N,K] row-major bf16. BK=32.
// LDS rows are 64B (32 bf16); 16B-slot s of row r holds global col16 (s ^ ((r>>1)&3)).
template<int BMt, int BNt, bool BIAS, bool RELU, bool RESID, bool OUTF, bool OUTB>
__global__ __launch_bounds__(256) void gemm2(
    const short* __restrict__ A, const short* __restrict__ Bb,
    const float* __restrict__ biasb, const float* __restrict__ resid,
    float* __restrict__ Cfb, short* __restrict__ Cbb,
    int M, int N, int K, float scale,
    int zdiv, long bs1, long bs2, int bb1, int bb2, long cStr)
{
  constexpr int MR = BMt / 32, NR = BNt / 32;
  constexpr int WMt = BMt / 2, WNt = BNt / 2;
  constexpr int ACALLS = BMt / 16;
  constexpr int CPW = (BMt + BNt) / 64;   // staging calls per wave

  const int z = blockIdx.z;
  const short* Bp = Bb + (long)(z / zdiv) * bs1 + (long)(z % zdiv) * bs2;
  const float* bias = BIAS ? (biasb + (z / zdiv) * bb1 + (z % zdiv) * bb2) : nullptr;

  const int m0 = blockIdx.y * BMt;
  const int n0 = blockIdx.x * BNt;

  __shared__ __align__(16) short As[BMt * 32];
  __shared__ __align__(16) short Bs[BNt * 32];

  const int tid = threadIdx.x;
  const int lane = tid & 63;
  const int w = tid >> 6;

  // staging source pointers (per-lane global, swizzled col) + wave-uniform LDS dests
  const short* srcs[CPW];
  short* ldss[CPW];
  {
    const int rl = lane >> 2;
    const int col16 = (lane & 3) ^ ((rl >> 1) & 3);
#pragma unroll
    for (int c = 0; c < CPW; ++c) {
      int q = w * CPW + c;
      if (q < ACALLS) {
        int row = q * 16 + rl;
        srcs[c] = A + (long)(m0 + row) * K + col16 * 8;
        ldss[c] = &As[q * 512];
      } else {
        int g = q - ACALLS;
        int row = g * 16 + rl;
        srcs[c] = Bp + (long)(n0 + row) * K + col16 * 8;
        ldss[c] = &Bs[g * 512];
      }
    }
  }

  const int lrow = lane & 15;
  const int slot = (((lane >> 4) ^ ((lane >> 1) & 3))) * 8;  // swizzled 16B slot (in shorts)
  const int wm = (w >> 1) * WMt, wn = (w & 1) * WNt;

  f32x4 acc[MR][NR] = {};

  for (int k0 = 0; k0 < K; k0 += 32) {
#pragma unroll
    for (int c = 0; c < CPW; ++c) gload16(srcs[c], ldss[c]);
#pragma unroll
    for (int c = 0; c < CPW; ++c) srcs[c] += 32;
    __syncthreads();
    bf16x8 af[MR], bfv[NR];
#pragma unroll
    for (int f = 0; f < MR; ++f) af[f] = *(const bf16x8*)&As[(wm + f * 16 + lrow) * 32 + slot];
#pragma unroll
    for (int f = 0; f < NR; ++f) bfv[f] = *(const bf16x8*)&Bs[(wn + f * 16 + lrow) * 32 + slot];
#pragma unroll
    for (int i = 0; i < MR; ++i)
#pragma unroll
      for (int j = 0; j < NR; ++j)
        acc[i][j] = __builtin_amdgcn_mfma_f32_16x16x32_bf16(af[i], bfv[j], acc[i][j], 0, 0, 0);
    __syncthreads();
  }

  float* Cf = OUTF ? (Cfb + (long)z * cStr) : nullptr;
  short* Cb = OUTB ? (Cbb + (long)z * cStr) : nullptr;
  const int crow = (lane >> 4) * 4;
  const int ccol = lane & 15;
#pragma unroll
  for (int i = 0; i < MR; ++i) {
#pragma unroll
    for (int j = 0; j < NR; ++j) {
      int gc = n0 + wn + j * 16 + ccol;
      float bv = BIAS ? bias[gc] : 0.f;
#pragma unroll
      for (int r = 0; r < 4; ++r) {
        int gr = m0 + wm + i * 16 + crow + r;
        long off = (long)gr * N + gc;
        float v = acc[i][j][r] * scale + bv;
        if (RESID) v += resid[off];
        if (RELU) v = v > 0.f ? v : 0.f;
        if (OUTF) Cf[off] = v;
        if (OUTB) Cb[off] = f2b(v);
      }
    }
  }
}

// ---------------- f32 [K,N] -> bf16 [N,K] transpose-convert (batched z) ----------------
__global__ __launch_bounds__(256) void tconv_k(const float* __restrict__ in, short* __restrict__ out,
                                               int K, int N) {
  __shared__ float t[32][33];
  long zo = (long)blockIdx.z * K * N;
  int n0 = blockIdx.x * 32, k0 = blockIdx.y * 32;
  int tx = threadIdx.x & 31, ty = threadIdx.x >> 5;
#pragma unroll
  for (int i = 0; i < 4; ++i)
    t[ty + i * 8][tx] = in[zo + (long)(k0 + ty + i * 8) * N + n0 + tx];
  __syncthreads();
#pragma unroll
  for (int i = 0; i < 4; ++i)
    out[zo + (long)(n0 + ty + i * 8) * K + k0 + tx] = f2b(t[tx][ty + i * 8]);
}

// ---------------- bf16 [R,C] -> bf16 [C,R] transpose (batched z) ----------------
__global__ __launch_bounds__(256) void tb16_k(const short* __restrict__ in, short* __restrict__ out,
                                              int R, int C) {
  __shared__ short t[32][34];
  long zo = (long)blockIdx.z * R * C;
  int c0 = blockIdx.x * 32, r0 = blockIdx.y * 32;
  int tx = threadIdx.x & 31, ty = threadIdx.x >> 5;
#pragma unroll
  for (int i = 0; i < 4; ++i)
    t[ty + i * 8][tx] = in[zo + (long)(r0 + ty + i * 8) * C + c0 + tx];
  __syncthreads();
#pragma unroll
  for (int i = 0; i < 4; ++i)
    out[zo + (long)(c0 + ty + i * 8) * R + r0 + tx] = t[tx][ty + i * 8];
}

// ------------------------------ softmax over rows of [SS,SS] ------------------------------
__global__ __launch_bounds__(256) void softmax_k(const float* __restrict__ Sc, short* __restrict__ P) {
  const int row = blockIdx.x;
  const float* src = Sc + (long)row * SS;
  const int tid = threadIdx.x;
  float vals[8];
  float mx = -3.0e38f;
#pragma unroll
  for (int i = 0; i < 8; ++i) {
    vals[i] = src[tid + i * 256];
    mx = fmaxf(mx, vals[i]);
  }
#pragma unroll
  for (int o = 32; o; o >>= 1) mx = fmaxf(mx, __shfl_xor(mx, o));
  __shared__ float r1[4], r2[4];
  if ((tid & 63) == 0) r1[tid >> 6] = mx;
  __syncthreads();
  mx = fmaxf(fmaxf(r1[0], r1[1]), fmaxf(r1[2], r1[3]));
  float sum = 0.f;
#pragma unroll
  for (int i = 0; i < 8; ++i) { vals[i] = __expf(vals[i] - mx); sum += vals[i]; }
#pragma unroll
  for (int o = 32; o; o >>= 1) sum += __shfl_xor(sum, o);
  if ((tid & 63) == 0) r2[tid >> 6] = sum;
  __syncthreads();
  sum = r2[0] + r2[1] + r2[2] + r2[3];
  float inv = 1.0f / sum;
  short* dst = P + (long)row * SS;
#pragma unroll
  for (int i = 0; i < 8; ++i) dst[tid + i * 256] = f2b(vals[i] * inv);
}

// ------------------------------ LayerNorm over rows of [SS,HHd] ------------------------------
__global__ __launch_bounds__(256) void ln_k(const float* __restrict__ X, const float* __restrict__ w,
                                            const float* __restrict__ b, float* __restrict__ Yf,
                                            short* __restrict__ Yb) {
  const int row = blockIdx.x;
  const int tid = threadIdx.x;
  const float* src = X + (long)row * HHd;
  float x0 = src[tid], x1 = src[tid + 256];
  float s = x0 + x1;
#pragma unroll
  for (int o = 32; o; o >>= 1) s += __shfl_xor(s, o);
  __shared__ float r1[4], r2[4];
  if ((tid & 63) == 0) r1[tid >> 6] = s;
  __syncthreads();
  float mean = (r1[0] + r1[1] + r1[2] + r1[3]) * (1.f / HHd);
  float d0 = x0 - mean, d1 = x1 - mean;
  float q = d0 * d0 + d1 * d1;
#pragma unroll
  for (int o = 32; o; o >>= 1) q += __shfl_xor(q, o);
  if ((tid & 63) == 0) r2[tid >> 6] = q;
  __syncthreads();
  float var = (r2[0] + r2[1] + r2[2] + r2[3]) * (1.f / HHd);
  float rs = rsqrtf(var + 1e-5f);
  float o0 = d0 * rs * w[tid] + b[tid];
  float o1 = d1 * rs * w[tid + 256] + b[tid + 256];
  long base = (long)row * HHd;
  Yf[base + tid] = o0; Yf[base + tid + 256] = o1;
  Yb[base + tid] = f2b(o0); Yb[base + tid + 256] = f2b(o1);
}

// ------------------------------ embedding gather ------------------------------
__global__ __launch_bounds__(256) void gather_k(const int* __restrict__ sent, const float* __restrict__ emb,
                                                float* __restrict__ hf, short* __restrict__ hb,
                                                float* __restrict__ yf, short* __restrict__ yb) {
  long i = (long)blockIdx.x * 256 + threadIdx.x;
  int s = (int)(i >> 9);
  int hcol = (int)(i & 511);
  float v = emb[(long)sent[s] * HHd + hcol];
  short bb = f2b(v);
  hf[i] = v; yf[i] = v; hb[i] = bb; yb[i] = bb;
}

// ------------------------------ feats: [SS,HHd] @ [HHd,TTd] + b (f32) ------------------------------
__global__ __launch_bounds__(256) void feats_k(const float* __restrict__ Y, const float* __restrict__ W,
                                               const float* __restrict__ b, float* __restrict__ feats) {
  __shared__ float ys[8 * HHd];
  const int row0 = blockIdx.x * 8;
  for (int i = threadIdx.x; i < 8 * HHd; i += 256) ys[i] = Y[(long)row0 * HHd + i];
  __syncthreads();
  const int n = threadIdx.x & 31, r = threadIdx.x >> 5;
  float acc = b[n];
  const float* yr = &ys[r * HHd];
  for (int k = 0; k < HHd; ++k) acc = fmaf(yr[k], W[k * TTd + n], acc);
  feats[(long)(row0 + r) * TTd + n] = acc;
}

// ------------------------------ Viterbi (single block, 64 threads) ------------------------------
// lane&31 = tag (replicated in both halves); lane>>5 = prev-half. No redistribution shuffle.
__global__ __launch_bounds__(64) void viterbi_k(const float* __restrict__ feats,
                                                const float* __restrict__ trans,
                                                float* __restrict__ out,
                                                unsigned* __restrict__ bp4) {
  __shared__ float fbuf[2][2048];
  __shared__ float fvS[32];
  __shared__ unsigned char GsL[64 * 32];
  __shared__ unsigned char bnd[64];
  const int lane = threadIdx.x;
  const int n = lane & 31;
  const int h = lane >> 5;
  const int p0 = h << 4;
  float tr[16];
#pragma unroll
  for (int j = 0; j < 16; ++j) tr[j] = trans[n * 32 + p0 + j];
  float fv = (n == 30) ? 0.f : -10000.f;

  const float4* f4 = (const float4*)feats;
  float4 pf[8];
#pragma unroll
  for (int i = 0; i < 8; ++i) pf[i] = f4[i * 64 + lane];

  unsigned pack = 0;
  for (int t = 0; t < 2048; ++t) {
    if ((t & 63) == 0) {
      int ch = t >> 6;
      int cur = ch & 1;
#pragma unroll
      for (int i = 0; i < 8; ++i) *(float4*)&fbuf[cur][i * 256 + lane * 4] = pf[i];
      if (ch + 1 < 32) {
#pragma unroll
        for (int i = 0; i < 8; ++i) pf[i] = f4[(ch + 1) * 512 + i * 64 + lane];
      }
      __syncthreads();
    }
    float c[16];
#pragma unroll
    for (int j = 0; j < 16; ++j) c[j] = __shfl(fv, p0 + j);
#pragma unroll
    for (int j = 0; j < 16; ++j) c[j] += tr[j];
    float v8[8]; int i8a[8];
#pragma unroll
    for (int j = 0; j < 8; ++j) {
      bool g = c[2 * j + 1] > c[2 * j];
      v8[j] = g ? c[2 * j + 1] : c[2 * j];
      i8a[j] = g ? 2 * j + 1 : 2 * j;
    }
    float v4[4]; int i4a[4];
#pragma unroll
    for (int j = 0; j < 4; ++j) {
      bool g = v8[2 * j + 1] > v8[2 * j];
      v4[j] = g ? v8[2 * j + 1] : v8[2 * j];
      i4a[j] = g ? i8a[2 * j + 1] : i8a[2 * j];
    }
    float v2[2]; int i2a[2];
#pragma unroll
    for (int j = 0; j < 2; ++j) {
      bool g = v4[2 * j + 1] > v4[2 * j];
      v2[j] = g ? v4[2 * j + 1] : v4[2 * j];
      i2a[j] = g ? i4a[2 * j + 1] : i4a[2 * j];
    }
    bool g1 = v2[1] > v2[0];
    float bv = g1 ? v2[1] : v2[0];
    int bi = p0 + (g1 ? i2a[1] : i2a[0]);
    float ov = __shfl_xor(bv, 32);
    int oi = __shfl_xor(bi, 32);
    bool takeo = h ? (ov >= bv) : (ov > bv);
    float m = takeo ? ov : bv;
    int mi = takeo ? oi : bi;
    fv = m + fbuf[(t >> 6) & 1][(t & 63) * 32 + n];
    pack |= (unsigned)mi << ((t & 3) * 8);
    if ((t & 3) == 3) {
      if (!h) bp4[(t >> 2) * 32 + n] = pack;
      pack = 0;
    }
  }
  if (lane < 32) fvS[lane] = fv;
  __threadfence();
  __syncthreads();

  const unsigned char* bp8 = (const unsigned char*)bp4;
  // chunk map composition: lane c composes steps [32c, 32c+32) (L2-hot global reads)
  unsigned char g[32];
#pragma unroll
  for (int j = 0; j < 32; ++j) g[j] = (unsigned char)j;
  for (int s = 31; s >= 0; --s) {
    int t = lane * 32 + s;
    const unsigned char* rowp = bp8 + (t >> 2) * 128 + (t & 3);
#pragma unroll
    for (int j = 0; j < 32; ++j) g[j] = rowp[g[j] * 4];
  }
#pragma unroll
  for (int j = 0; j < 32; ++j) GsL[lane * 32 + j] = g[j];
  __syncthreads();

  if (lane == 0) {
    float best = -3.0e38f; int bt = 0;
    for (int j = 0; j < 32; ++j) {
      float v = fvS[j] + trans[31 * 32 + j];
      if (v > best) { best = v; bt = j; }
    }
    out[0] = best;
    bnd[63] = (unsigned char)bt;
    for (int cc = 63; cc >= 1; --cc) bnd[cc - 1] = GsL[cc * 32 + bnd[cc]];
  }
  __syncthreads();

  int x = bnd[lane];
  out[1 + lane * 32 + 31] = (float)x;
  for (int k = 30; k >= 0; --k) {
    int t = lane * 32 + k + 1;
    x = bp8[(t >> 2) * 128 + x * 4 + (t & 3)];
    out[1 + lane * 32 + k] = (float)x;
  }
}

// ------------------------------ host ------------------------------
extern "C" void kernel_launch(void* const* d_in, const int* in_sizes, int n_in,
                              void* d_out, int out_size, void* d_ws, size_t ws_size,
                              hipStream_t stream) {
  (void)in_sizes; (void)n_in; (void)out_size; (void)ws_size;
  const int H = HHd, F = FFd, S = SS, L = LLd;
  const long HH2 = (long)H * H;
  const long SH = (long)S * H;
  const long HF = (long)H * F;

  const int*   sent = (const int*)d_in[0];
  const float* embd = (const float*)d_in[1];
  const float* eaw  = (const float*)d_in[2];
  const float* eab  = (const float*)d_in[3];
  const float* ew1  = (const float*)d_in[4];
  const float* eb1  = (const float*)d_in[5];
  const float* ew2  = (const float*)d_in[6];
  const float* eb2  = (const float*)d_in[7];
  const float* elnw = (const float*)d_in[8];
  const float* elnb = (const float*)d_in[9];
  const float* daw  = (const float*)d_in[10];
  const float* dab  = (const float*)d_in[11];
  const float* dw1  = (const float*)d_in[12];
  const float* db1  = (const float*)d_in[13];
  const float* dw2  = (const float*)d_in[14];
  const float* db2  = (const float*)d_in[15];
  const float* dlnw = (const float*)d_in[16];
  const float* dlnb = (const float*)d_in[17];
  const float* enw  = (const float*)d_in[18];
  const float* enb  = (const float*)d_in[19];
  const float* dnw  = (const float*)d_in[20];
  const float* dnb  = (const float*)d_in[21];
  const float* h2tw = (const float*)d_in[22];
  const float* h2tb = (const float*)d_in[23];
  const float* trns = (const float*)d_in[24];

  char* p = (char*)d_ws;
  auto alloc = [&](size_t bytes) -> char* {
    char* r = p;
    p += (bytes + 255) & ~(size_t)255;
    return r;
  };
  // transposed bf16 weights
  short* wEAT = (short*)alloc((size_t)L * 4 * HH2 * 2);
  short* wDAT = (short*)alloc((size_t)L * 8 * HH2 * 2);
  short* wE1T = (short*)alloc((size_t)L * HF * 2);
  short* wE2T = (short*)alloc((size_t)L * HF * 2);
  short* wD1T = (short*)alloc((size_t)L * HF * 2);
  short* wD2T = (short*)alloc((size_t)L * HF * 2);
  // activations
  float* h_f  = (float*)alloc(SH * 4);
  short* h_b  = (short*)alloc(SH * 2);
  float* y_f  = (float*)alloc(SH * 4);
  short* y_b  = (short*)alloc(SH * 2);
  float* tmpf = (float*)alloc(SH * 4);
  short* qkvb = (short*)alloc(3 * SH * 2);
  float* scf  = (float*)alloc((size_t)S * S * 4);   // also stages cross-V bf16 pre-decoder
  short* P_b  = (short*)alloc((size_t)S * S * 2);
  short* attb = (short*)alloc(SH * 2);
  short* ff1b = (short*)alloc((size_t)S * F * 2);   // also holds V^T (2MB) during attention
  short* memb = (short*)alloc(SH * 2);
  short* ckb  = (short*)alloc((size_t)L * SH * 2);
  short* cvT  = (short*)alloc((size_t)L * SH * 2);
  float* ftsf = (float*)alloc((size_t)S * TTd * 4);
  unsigned* bp4 = (unsigned*)alloc((size_t)512 * 32 * 4);

  short* vtb = ff1b;           // V^T scratch aliases ff1b (disjoint lifetimes)
  short* cvS = (short*)scf;    // cross-V staging aliases scf (pre-decoder only)

  const int ZBIG = 1 << 20;
  const float RSQ = 0.04419417382415922f;  // 1/sqrt(512)

  // ---- transposed weight conversion ----
  tconv_k<<<dim3(16, 16, L * 4), 256, 0, stream>>>(eaw, wEAT, H, H);
  tconv_k<<<dim3(16, 16, L * 8), 256, 0, stream>>>(daw, wDAT, H, H);
  tconv_k<<<dim3(64, 16, L), 256, 0, stream>>>(ew1, wE1T, H, F);
  tconv_k<<<dim3(16, 64, L), 256, 0, stream>>>(ew2, wE2T, F, H);
  tconv_k<<<dim3(64, 16, L), 256, 0, stream>>>(dw1, wD1T, H, F);
  tconv_k<<<dim3(16, 64, L), 256, 0, stream>>>(dw2, wD2T, F, H);

  gather_k<<<dim3((unsigned)(SH / 256)), 256, 0, stream>>>(sent, embd, h_f, h_b, y_f, y_b);

  // gemm variants
  auto G_qkv = gemm2<128, 64, true, false, false, false, true>;   // bias -> bf16
  auto G_sc  = gemm2<128, 128, false, false, false, true, false>; // scale -> f32
  auto G_pv  = gemm2<128, 64, false, false, false, false, true>;  // -> bf16
  auto G_out = gemm2<128, 64, true, false, true, true, false>;    // bias+resid -> f32
  auto G_ff1 = gemm2<128, 128, true, true, false, false, true>;   // bias+relu -> bf16

  dim3 g64(8, 16, 1), g128(16, 16, 1);

  // ---------------- encoder ----------------
  for (int i = 0; i < L; ++i) {
    G_qkv<<<dim3(8, 16, 3), 256, 0, stream>>>(
        h_b, wEAT + (size_t)i * 4 * HH2, eab + (size_t)i * 4 * H, nullptr, nullptr, qkvb,
        S, H, H, 1.f, ZBIG, 0, HH2, 0, H, SH);
    tb16_k<<<dim3(16, 64, 1), 256, 0, stream>>>(qkvb + 2 * SH, vtb, S, H);
    G_sc<<<g128, 256, 0, stream>>>(
        qkvb, qkvb + SH, nullptr, nullptr, scf, nullptr,
        S, S, H, RSQ, 1, 0, 0, 0, 0, 0);
    softmax_k<<<dim3(S), 256, 0, stream>>>(scf, P_b);
    G_pv<<<g64, 256, 0, stream>>>(
        P_b, vtb, nullptr, nullptr, nullptr, attb,
        S, H, S, 1.f, 1, 0, 0, 0, 0, 0);
    G_out<<<g64, 256, 0, stream>>>(
        attb, wEAT + ((size_t)i * 4 + 3) * HH2, eab + ((size_t)i * 4 + 3) * H, h_f, tmpf, nullptr,
        S, H, H, 1.f, 1, 0, 0, 0, 0, 0);
    ln_k<<<dim3(S), 256, 0, stream>>>(tmpf, elnw + (size_t)(i * 2) * H, elnb + (size_t)(i * 2) * H, h_f, h_b);
    G_ff1<<<g128, 256, 0, stream>>>(
        h_b, wE1T + (size_t)i * HF, eb1 + (size_t)i * F, nullptr, nullptr, ff1b,
        S, F, H, 1.f, 1, 0, 0, 0, 0, 0);
    G_out<<<g64, 256, 0, stream>>>(
        ff1b, wE2T + (size_t)i * HF, eb2 + (size_t)i * H, h_f, tmpf, nullptr,
        S, H, F, 1.f, 1, 0, 0, 0, 0, 0);
    ln_k<<<dim3(S), 256, 0, stream>>>(tmpf, elnw + (size_t)(i * 2 + 1) * H, elnb + (size_t)(i * 2 + 1) * H, h_f, h_b);
  }
  // mem = LN(h) -> memb (bf16)
  ln_k<<<dim3(S), 256, 0, stream>>>(h_f, enw, enb, tmpf, memb);

  // cross K (j=5) and cross V (j=6) for all layers, batched z=0..5
  G_qkv<<<dim3(8, 16, L), 256, 0, stream>>>(
      memb, wDAT + 5 * HH2, dab + 5 * H, nullptr, nullptr, ckb,
      S, H, H, 1.f, 1, 8 * HH2, 0, 8 * H, 0, SH);
  G_qkv<<<dim3(8, 16, L), 256, 0, stream>>>(
      memb, wDAT + 6 * HH2, dab + 6 * H, nullptr, nullptr, cvS,
      S, H, H, 1.f, 1, 8 * HH2, 0, 8 * H, 0, SH);
  tb16_k<<<dim3(16, 64, L), 256, 0, stream>>>(cvS, cvT, S, H);

  // ---------------- decoder ----------------
  for (int i = 0; i < L; ++i) {
    G_qkv<<<dim3(8, 16, 3), 256, 0, stream>>>(
        y_b, wDAT + (size_t)i * 8 * HH2, dab + (size_t)i * 8 * H, nullptr, nullptr, qkvb,
        S, H, H, 1.f, ZBIG, 0, HH2, 0, H, SH);
    tb16_k<<<dim3(16, 64, 1), 256, 0, stream>>>(qkvb + 2 * SH, vtb, S, H);
    G_sc<<<g128, 256, 0, stream>>>(
        qkvb, qkvb + SH, nullptr, nullptr, scf, nullptr,
        S, S, H, RSQ, 1, 0, 0, 0, 0, 0);
    softmax_k<<<dim3(S), 256, 0, stream>>>(scf, P_b);
    G_pv<<<g64, 256, 0, stream>>>(
        P_b, vtb, nullptr, nullptr, nullptr, attb,
        S, H, S, 1.f, 1, 0, 0, 0, 0, 0);
    G_out<<<g64, 256, 0, stream>>>(
        attb, wDAT + ((size_t)i * 8 + 3) * HH2, dab + ((size_t)i * 8 + 3) * H, y_f, tmpf, nullptr,
        S, H, H, 1.f, 1, 0, 0, 0, 0, 0);
    ln_k<<<dim3(S), 256, 0, stream>>>(tmpf, dlnw + (size_t)(i * 3) * H, dlnb + (size_t)(i * 3) * H, y_f, y_b);
    // cross-attn
    G_qkv<<<dim3(8, 16, 1), 256, 0, stream>>>(
        y_b, wDAT + ((size_t)i * 8 + 4) * HH2, dab + ((size_t)i * 8 + 4) * H, nullptr, nullptr, qkvb,
        S, H, H, 1.f, ZBIG, 0, HH2, 0, H, SH);
    G_sc<<<g128, 256, 0, stream>>>(
        qkvb, ckb + (size_t)i * SH, nullptr, nullptr, scf, nullptr,
        S, S, H, RSQ, 1, 0, 0, 0, 0, 0);
    softmax_k<<<dim3(S), 256, 0, stream>>>(scf, P_b);
    G_pv<<<g64, 256, 0, stream>>>(
        P_b, cvT + (size_t)i * SH, nullptr, nullptr, nullptr, attb,
        S, H, S, 1.f, 1, 0, 0, 0, 0, 0);
    G_out<<<g64, 256, 0, stream>>>(
        attb, wDAT + ((size_t)i * 8 + 7) * HH2, dab + ((size_t)i * 8 + 7) * H, y_f, tmpf, nullptr,
        S, H, H, 1.f, 1, 0, 0, 0, 0, 0);
    ln_k<<<dim3(S), 256, 0, stream>>>(tmpf, dlnw + (size_t)(i * 3 + 1) * H, dlnb + (size_t)(i * 3 + 1) * H, y_f, y_b);
    // FFN
    G_ff1<<<g128, 256, 0, stream>>>(
        y_b, wD1T + (size_t)i * HF, db1 + (size_t)i * F, nullptr, nullptr, ff1b,
        S, F, H, 1.f, 1, 0, 0, 0, 0, 0);
    G_out<<<g64, 256, 0, stream>>>(
        ff1b, wD2T + (size_t)i * HF, db2 + (size_t)i * H, y_f, tmpf, nullptr,
        S, H, F, 1.f, 1, 0, 0, 0, 0, 0);
    ln_k<<<dim3(S), 256, 0, stream>>>(tmpf, dlnw + (size_t)(i * 3 + 2) * H, dlnb + (size_t)(i * 3 + 2) * H, y_f, y_b);
  }
  // final norm + feats + viterbi
  ln_k<<<dim3(S), 256, 0, stream>>>(y_f, dnw, dnb, tmpf, memb);
  feats_k<<<dim3(S / 8), 256, 0, stream>>>(tmpf, h2tw, h2tb, ftsf);
  viterbi_k<<<dim3(1), 64, 0, stream>>>(ftsf, trns, (float*)d_out, bp4);
}

// Round 3
// 2186.691 us; speedup vs baseline: 2.8850x; 1.5090x over previous
//
#include <hip/hip_runtime.h>
#include <cstdint>

#define SS 2048
#define HHd 512
#define FFd 2048
#define TTd 32
#define LLd 6
#define VW 32
#define VC 64

typedef float f32x4 __attribute__((ext_vector_type(4)));
typedef __bf16 bf16x8 __attribute__((ext_vector_type(8)));
typedef short short8v __attribute__((ext_vector_type(8)));
typedef short short4v __attribute__((ext_vector_type(4)));

__device__ __forceinline__ short f2b(float f) {
  unsigned u = __builtin_bit_cast(unsigned, f);
  u += 0x7fffu + ((u >> 16) & 1u);
  return (short)(u >> 16);
}

typedef const __attribute__((address_space(1))) void gv_t;
typedef __attribute__((address_space(3))) void lv_t;
__device__ __forceinline__ void gload16(const void* g, void* l) {
  __builtin_amdgcn_global_load_lds((gv_t*)g, (lv_t*)l, 16, 0, 0);
}

// ------------------------------ GEMM (all-TB, m97 structure) ------------------------------
// C[M,N] = A[M,K] @ B^T where B is [N,K] row-major bf16. BK=32.
template<int BMt, int BNt, bool BIAS, bool RELU, bool RESID, bool OUTF, bool OUTB>
__global__ __launch_bounds__(256) void gemm2(
    const short* __restrict__ A, const short* __restrict__ Bb,
    const float* __restrict__ biasb, const float* __restrict__ resid,
    float* __restrict__ Cfb, short* __restrict__ Cbb,
    int M, int N, int K, float scale,
    int zdiv, long bs1, long bs2, int bb1, int bb2, long cStr)
{
  constexpr int MR = BMt / 32, NR = BNt / 32;
  constexpr int WMt = BMt / 2, WNt = BNt / 2;
  constexpr int ACALLS = BMt / 16;
  constexpr int CPW = (BMt + BNt) / 64;

  const int z = blockIdx.z;
  const short* Bp = Bb + (long)(z / zdiv) * bs1 + (long)(z % zdiv) * bs2;
  const float* bias = BIAS ? (biasb + (z / zdiv) * bb1 + (z % zdiv) * bb2) : nullptr;

  const int m0 = blockIdx.y * BMt;
  const int n0 = blockIdx.x * BNt;

  __shared__ __align__(16) short As[BMt * 32];
  __shared__ __align__(16) short Bs[BNt * 32];

  const int tid = threadIdx.x;
  const int lane = tid & 63;
  const int w = tid >> 6;

  const short* srcs[CPW];
  short* ldss[CPW];
  {
    const int rl = lane >> 2;
    const int col16 = (lane & 3) ^ ((rl >> 1) & 3);
#pragma unroll
    for (int c = 0; c < CPW; ++c) {
      int q = w * CPW + c;
      if (q < ACALLS) {
        int row = q * 16 + rl;
        srcs[c] = A + (long)(m0 + row) * K + col16 * 8;
        ldss[c] = &As[q * 512];
      } else {
        int g = q - ACALLS;
        int row = g * 16 + rl;
        srcs[c] = Bp + (long)(n0 + row) * K + col16 * 8;
        ldss[c] = &Bs[g * 512];
      }
    }
  }

  const int lrow = lane & 15;
  const int slot = (((lane >> 4) ^ ((lane >> 1) & 3))) * 8;
  const int wm = (w >> 1) * WMt, wn = (w & 1) * WNt;

  f32x4 acc[MR][NR] = {};

  for (int k0 = 0; k0 < K; k0 += 32) {
#pragma unroll
    for (int c = 0; c < CPW; ++c) gload16(srcs[c], ldss[c]);
#pragma unroll
    for (int c = 0; c < CPW; ++c) srcs[c] += 32;
    __syncthreads();
    bf16x8 af[MR], bfv[NR];
#pragma unroll
    for (int f = 0; f < MR; ++f) af[f] = *(const bf16x8*)&As[(wm + f * 16 + lrow) * 32 + slot];
#pragma unroll
    for (int f = 0; f < NR; ++f) bfv[f] = *(const bf16x8*)&Bs[(wn + f * 16 + lrow) * 32 + slot];
#pragma unroll
    for (int i = 0; i < MR; ++i)
#pragma unroll
      for (int j = 0; j < NR; ++j)
        acc[i][j] = __builtin_amdgcn_mfma_f32_16x16x32_bf16(af[i], bfv[j], acc[i][j], 0, 0, 0);
    __syncthreads();
  }

  float* Cf = OUTF ? (Cfb + (long)z * cStr) : nullptr;
  short* Cb = OUTB ? (Cbb + (long)z * cStr) : nullptr;
  const int crow = (lane >> 4) * 4;
  const int ccol = lane & 15;
#pragma unroll
  for (int i = 0; i < MR; ++i) {
#pragma unroll
    for (int j = 0; j < NR; ++j) {
      int gc = n0 + wn + j * 16 + ccol;
      float bv = BIAS ? bias[gc] : 0.f;
#pragma unroll
      for (int r = 0; r < 4; ++r) {
        int gr = m0 + wm + i * 16 + crow + r;
        long off = (long)gr * N + gc;
        float v = acc[i][j][r] * scale + bv;
        if (RESID) v += resid[off];
        if (RELU) v = v > 0.f ? v : 0.f;
        if (OUTF) Cf[off] = v;
        if (OUTB) Cb[off] = f2b(v);
      }
    }
  }
}

// ---------------- f32 [K,N] -> bf16 [N,K] transpose-convert (batched z) ----------------
__global__ __launch_bounds__(256) void tconv_k(const float* __restrict__ in, short* __restrict__ out,
                                               int K, int N) {
  __shared__ float t[32][33];
  long zo = (long)blockIdx.z * K * N;
  int n0 = blockIdx.x * 32, k0 = blockIdx.y * 32;
  int tx = threadIdx.x & 31, ty = threadIdx.x >> 5;
#pragma unroll
  for (int i = 0; i < 4; ++i)
    t[ty + i * 8][tx] = in[zo + (long)(k0 + ty + i * 8) * N + n0 + tx];
  __syncthreads();
#pragma unroll
  for (int i = 0; i < 4; ++i)
    out[zo + (long)(n0 + ty + i * 8) * K + k0 + tx] = f2b(t[tx][ty + i * 8]);
}

// ---------------- bf16 [R,C] -> bf16 [C,R] transpose (batched z) ----------------
__global__ __launch_bounds__(256) void tb16_k(const short* __restrict__ in, short* __restrict__ out,
                                              int R, int C) {
  __shared__ short t[32][34];
  long zo = (long)blockIdx.z * R * C;
  int c0 = blockIdx.x * 32, r0 = blockIdx.y * 32;
  int tx = threadIdx.x & 31, ty = threadIdx.x >> 5;
#pragma unroll
  for (int i = 0; i < 4; ++i)
    t[ty + i * 8][tx] = in[zo + (long)(r0 + ty + i * 8) * C + c0 + tx];
  __syncthreads();
#pragma unroll
  for (int i = 0; i < 4; ++i)
    out[zo + (long)(c0 + ty + i * 8) * R + r0 + tx] = t[tx][ty + i * 8];
}

// ------------------------------ softmax over rows of [SS,SS] ------------------------------
__global__ __launch_bounds__(256) void softmax_k(const float* __restrict__ Sc, short* __restrict__ P) {
  const int row = blockIdx.x;
  const float* src = Sc + (long)row * SS;
  const int tid = threadIdx.x;
  float vals[8];
  float mx = -3.0e38f;
#pragma unroll
  for (int i = 0; i < 8; ++i) {
    vals[i] = src[tid + i * 256];
    mx = fmaxf(mx, vals[i]);
  }
#pragma unroll
  for (int o = 32; o; o >>= 1) mx = fmaxf(mx, __shfl_xor(mx, o));
  __shared__ float r1[4], r2[4];
  if ((tid & 63) == 0) r1[tid >> 6] = mx;
  __syncthreads();
  mx = fmaxf(fmaxf(r1[0], r1[1]), fmaxf(r1[2], r1[3]));
  float sum = 0.f;
#pragma unroll
  for (int i = 0; i < 8; ++i) { vals[i] = __expf(vals[i] - mx); sum += vals[i]; }
#pragma unroll
  for (int o = 32; o; o >>= 1) sum += __shfl_xor(sum, o);
  if ((tid & 63) == 0) r2[tid >> 6] = sum;
  __syncthreads();
  sum = r2[0] + r2[1] + r2[2] + r2[3];
  float inv = 1.0f / sum;
  short* dst = P + (long)row * SS;
#pragma unroll
  for (int i = 0; i < 8; ++i) dst[tid + i * 256] = f2b(vals[i] * inv);
}

// ------------------------------ LayerNorm over rows of [SS,HHd] ------------------------------
__global__ __launch_bounds__(256) void ln_k(const float* __restrict__ X, const float* __restrict__ w,
                                            const float* __restrict__ b, float* __restrict__ Yf,
                                            short* __restrict__ Yb) {
  const int row = blockIdx.x;
  const int tid = threadIdx.x;
  const float* src = X + (long)row * HHd;
  float x0 = src[tid], x1 = src[tid + 256];
  float s = x0 + x1;
#pragma unroll
  for (int o = 32; o; o >>= 1) s += __shfl_xor(s, o);
  __shared__ float r1[4], r2[4];
  if ((tid & 63) == 0) r1[tid >> 6] = s;
  __syncthreads();
  float mean = (r1[0] + r1[1] + r1[2] + r1[3]) * (1.f / HHd);
  float d0 = x0 - mean, d1 = x1 - mean;
  float q = d0 * d0 + d1 * d1;
#pragma unroll
  for (int o = 32; o; o >>= 1) q += __shfl_xor(q, o);
  if ((tid & 63) == 0) r2[tid >> 6] = q;
  __syncthreads();
  float var = (r2[0] + r2[1] + r2[2] + r2[3]) * (1.f / HHd);
  float rs = rsqrtf(var + 1e-5f);
  float o0 = d0 * rs * w[tid] + b[tid];
  float o1 = d1 * rs * w[tid + 256] + b[tid + 256];
  long base = (long)row * HHd;
  Yf[base + tid] = o0; Yf[base + tid + 256] = o1;
  Yb[base + tid] = f2b(o0); Yb[base + tid + 256] = f2b(o1);
}

// ------------------------------ embedding gather ------------------------------
__global__ __launch_bounds__(256) void gather_k(const int* __restrict__ sent, const float* __restrict__ emb,
                                                float* __restrict__ hf, short* __restrict__ hb,
                                                float* __restrict__ yf, short* __restrict__ yb) {
  long i = (long)blockIdx.x * 256 + threadIdx.x;
  int s = (int)(i >> 9);
  int hcol = (int)(i & 511);
  float v = emb[(long)sent[s] * HHd + hcol];
  short bb = f2b(v);
  hf[i] = v; yf[i] = v; hb[i] = bb; yb[i] = bb;
}

// ------------------------------ feats: [SS,HHd] @ [HHd,TTd] + b (f32) ------------------------------
__global__ __launch_bounds__(256) void feats_k(const float* __restrict__ Y, const float* __restrict__ W,
                                               const float* __restrict__ b, float* __restrict__ feats) {
  __shared__ float ys[8 * HHd];
  const int row0 = blockIdx.x * 8;
  for (int i = threadIdx.x; i < 8 * HHd; i += 256) ys[i] = Y[(long)row0 * HHd + i];
  __syncthreads();
  const int n = threadIdx.x & 31, r = threadIdx.x >> 5;
  float acc = b[n];
  const float* yr = &ys[r * HHd];
  for (int k = 0; k < HHd; ++k) acc = fmaf(yr[k], W[k * TTd + n], acc);
  feats[(long)(row0 + r) * TTd + n] = acc;
}

// ============================== Parallel Viterbi ==============================
// max-plus scan: A_t[n][p] = trans[n][p] + feat[t][n]; fv_t = A_t (x) fv_{t-1}.
// P1: per-chunk matrix composition M_c (64 blocks x 256 thr).
__global__ __launch_bounds__(256) void vit_p1(const float* __restrict__ feats,
                                              const float* __restrict__ trans,
                                              float* __restrict__ Mc) {
  __shared__ float trS[1024];
  __shared__ float fS[VW * 32];
  __shared__ float Ga[32 * 33], Gb[32 * 33];
  const int c = blockIdx.x, tid = threadIdx.x;
  for (int i = tid; i < 1024; i += 256) trS[i] = trans[i];
  for (int i = tid; i < VW * 32; i += 256) fS[i] = feats[c * VW * 32 + i];
  __syncthreads();
  for (int i = tid; i < 1024; i += 256) {
    int n = i >> 5, q = i & 31;
    Ga[n * 33 + q] = trS[i] + fS[n];
  }
  __syncthreads();
  float* G = Ga;
  float* Gn = Gb;
  const int q = tid & 31, nb = (tid >> 5) * 4;
  for (int s = 1; s < VW; ++s) {
    float m0 = -3.0e38f, m1 = -3.0e38f, m2 = -3.0e38f, m3 = -3.0e38f;
    for (int pp = 0; pp < 32; ++pp) {
      float g = G[pp * 33 + q];
      m0 = fmaxf(m0, trS[(nb + 0) * 32 + pp] + g);
      m1 = fmaxf(m1, trS[(nb + 1) * 32 + pp] + g);
      m2 = fmaxf(m2, trS[(nb + 2) * 32 + pp] + g);
      m3 = fmaxf(m3, trS[(nb + 3) * 32 + pp] + g);
    }
    Gn[(nb + 0) * 33 + q] = m0 + fS[s * 32 + nb + 0];
    Gn[(nb + 1) * 33 + q] = m1 + fS[s * 32 + nb + 1];
    Gn[(nb + 2) * 33 + q] = m2 + fS[s * 32 + nb + 2];
    Gn[(nb + 3) * 33 + q] = m3 + fS[s * 32 + nb + 3];
    __syncthreads();
    float* t = G; G = Gn; Gn = t;
  }
  for (int i = tid; i < 1024; i += 256) Mc[c * 1024 + i] = G[(i >> 5) * 33 + (i & 31)];
}

// P2: serial chunk-boundary fv scan (1 wave) + terminal argmax.
__global__ __launch_bounds__(64) void vit_p2(const float* __restrict__ Mc,
                                             const float* __restrict__ trans,
                                             float* __restrict__ bfv,
                                             float* __restrict__ term,
                                             float* __restrict__ out) {
  const int lane = threadIdx.x, n = lane & 31, h = lane >> 5, p0 = h << 4;
  float fv = (n == 30) ? 0.f : -10000.f;
  if (lane < 32) bfv[lane] = fv;
  f32x4 A0, A1, A2, A3;
  {
    const float* M = Mc + n * 32 + p0;
    A0 = *(const f32x4*)(M); A1 = *(const f32x4*)(M + 4);
    A2 = *(const f32x4*)(M + 8); A3 = *(const f32x4*)(M + 12);
  }
  for (int c = 0; c < VC; ++c) {
    f32x4 B0 = A0, B1 = A1, B2 = A2, B3 = A3;
    if (c + 1 < VC) {
      const float* M = Mc + (c + 1) * 1024 + n * 32 + p0;
      B0 = *(const f32x4*)(M); B1 = *(const f32x4*)(M + 4);
      B2 = *(const f32x4*)(M + 8); B3 = *(const f32x4*)(M + 12);
    }
    float cnd[16];
#pragma unroll
    for (int j = 0; j < 16; ++j) {
      float mv = (j < 4) ? A0[j] : (j < 8) ? A1[j - 4] : (j < 12) ? A2[j - 8] : A3[j - 12];
      cnd[j] = __shfl(fv, p0 + j) + mv;
    }
    float t8[8];
#pragma unroll
    for (int j = 0; j < 8; ++j) t8[j] = fmaxf(cnd[2 * j], cnd[2 * j + 1]);
    float t4[4];
#pragma unroll
    for (int j = 0; j < 4; ++j) t4[j] = fmaxf(t8[2 * j], t8[2 * j + 1]);
    float bv = fmaxf(fmaxf(t4[0], t4[1]), fmaxf(t4[2], t4[3]));
    bv = fmaxf(bv, __shfl_xor(bv, 32));
    fv = bv;
    if (lane < 32) bfv[(c + 1) * 32 + n] = fv;
    A0 = B0; A1 = B1; A2 = B2; A3 = B3;
  }
  float v = fv + trans[31 * 32 + n];
  int idx = n;
#pragma unroll
  for (int o = 16; o; o >>= 1) {
    float ov = __shfl_xor(v, o);
    int oi = __shfl_xor(idx, o);
    if (ov > v || (ov == v && oi < idx)) { v = ov; idx = oi; }
  }
  if (lane == 0) { out[0] = v; term[0] = (float)idx; }
}

// P3: per-chunk forward re-run producing backpointers (VC waves, parallel).
__global__ __launch_bounds__(64) void vit_p3(const float* __restrict__ feats,
                                             const float* __restrict__ trans,
                                             const float* __restrict__ bfv,
                                             unsigned char* __restrict__ bp) {
  const int c = blockIdx.x, lane = threadIdx.x, n = lane & 31, h = lane >> 5, p0 = h << 4;
  float tr[16];
#pragma unroll
  for (int j = 0; j < 16; ++j) tr[j] = trans[n * 32 + p0 + j];
  float fv = bfv[c * 32 + n];
  float ft[VW];
  for (int s = 0; s < VW; ++s) ft[s] = feats[(c * VW + s) * 32 + n];
  for (int s = 0; s < VW; ++s) {
    float cd[16];
#pragma unroll
    for (int j = 0; j < 16; ++j) cd[j] = __shfl(fv, p0 + j) + tr[j];
    float v8[8]; int i8a[8];
#pragma unroll
    for (int j = 0; j < 8; ++j) {
      bool g = cd[2 * j + 1] > cd[2 * j];
      v8[j] = g ? cd[2 * j + 1] : cd[2 * j];
      i8a[j] = g ? 2 * j + 1 : 2 * j;
    }
    float v4[4]; int i4a[4];
#pragma unroll
    for (int j = 0; j < 4; ++j) {
      bool g = v8[2 * j + 1] > v8[2 * j];
      v4[j] = g ? v8[2 * j + 1] : v8[2 * j];
      i4a[j] = g ? i8a[2 * j + 1] : i8a[2 * j];
    }
    float v2[2]; int i2a[2];
#pragma unroll
    for (int j = 0; j < 2; ++j) {
      bool g = v4[2 * j + 1] > v4[2 * j];
      v2[j] = g ? v4[2 * j + 1] : v4[2 * j];
      i2a[j] = g ? i4a[2 * j + 1] : i4a[2 * j];
    }
    bool g1 = v2[1] > v2[0];
    float bv = g1 ? v2[1] : v2[0];
    int bi = p0 + (g1 ? i2a[1] : i2a[0]);
    float ov = __shfl_xor(bv, 32);
    int oi = __shfl_xor(bi, 32);
    bool takeo = h ? (ov >= bv) : (ov > bv);
    float m = takeo ? ov : bv;
    int mi = takeo ? oi : bi;
    if (!h) bp[(c * VW + s) * 32 + n] = (unsigned char)mi;
    fv = m + ft[s];
  }
}

// P4: backtrack via chunk map composition (1 block, 64 threads).
__global__ __launch_bounds__(64) void vit_p4(const unsigned char* __restrict__ bp,
                                             const float* __restrict__ term,
                                             float* __restrict__ out) {
  __shared__ unsigned char GsL[64 * 32];
  __shared__ unsigned char bnd[64];
  const int lane = threadIdx.x;
  unsigned char g[32];
#pragma unroll
  for (int j = 0; j < 32; ++j) g[j] = (unsigned char)j;
  for (int s = 31; s >= 0; --s) {
    const unsigned char* rowp = bp + (lane * 32 + s) * 32;
#pragma unroll
    for (int j = 0; j < 32; ++j) g[j] = rowp[g[j]];
  }
#pragma unroll
  for (int j = 0; j < 32; ++j) GsL[lane * 32 + j] = g[j];
  __syncthreads();
  if (lane == 0) {
    bnd[63] = (unsigned char)(int)term[0];
    for (int cc = 63; cc >= 1; --cc) bnd[cc - 1] = GsL[cc * 32 + bnd[cc]];
  }
  __syncthreads();
  int x = bnd[lane];
  out[1 + lane * 32 + 31] = (float)x;
  for (int k = 30; k >= 0; --k) {
    x = bp[(lane * 32 + k + 1) * 32 + x];
    out[1 + lane * 32 + k] = (float)x;
  }
}

// ------------------------------ host ------------------------------
extern "C" void kernel_launch(void* const* d_in, const int* in_sizes, int n_in,
                              void* d_out, int out_size, void* d_ws, size_t ws_size,
                              hipStream_t stream) {
  (void)in_sizes; (void)n_in; (void)out_size; (void)ws_size;
  const int H = HHd, F = FFd, S = SS, L = LLd;
  const long HH2 = (long)H * H;
  const long SH = (long)S * H;
  const long HF = (long)H * F;

  const int*   sent = (const int*)d_in[0];
  const float* embd = (const float*)d_in[1];
  const float* eaw  = (const float*)d_in[2];
  const float* eab  = (const float*)d_in[3];
  const float* ew1  = (const float*)d_in[4];
  const float* eb1  = (const float*)d_in[5];
  const float* ew2  = (const float*)d_in[6];
  const float* eb2  = (const float*)d_in[7];
  const float* elnw = (const float*)d_in[8];
  const float* elnb = (const float*)d_in[9];
  const float* daw  = (const float*)d_in[10];
  const float* dab  = (const float*)d_in[11];
  const float* dw1  = (const float*)d_in[12];
  const float* db1  = (const float*)d_in[13];
  const float* dw2  = (const float*)d_in[14];
  const float* db2  = (const float*)d_in[15];
  const float* dlnw = (const float*)d_in[16];
  const float* dlnb = (const float*)d_in[17];
  const float* enw  = (const float*)d_in[18];
  const float* enb  = (const float*)d_in[19];
  const float* dnw  = (const float*)d_in[20];
  const float* dnb  = (const float*)d_in[21];
  const float* h2tw = (const float*)d_in[22];
  const float* h2tb = (const float*)d_in[23];
  const float* trns = (const float*)d_in[24];

  char* p = (char*)d_ws;
  auto alloc = [&](size_t bytes) -> char* {
    char* r = p;
    p += (bytes + 255) & ~(size_t)255;
    return r;
  };
  short* wEAT = (short*)alloc((size_t)L * 4 * HH2 * 2);
  short* wDAT = (short*)alloc((size_t)L * 8 * HH2 * 2);
  short* wE1T = (short*)alloc((size_t)L * HF * 2);
  short* wE2T = (short*)alloc((size_t)L * HF * 2);
  short* wD1T = (short*)alloc((size_t)L * HF * 2);
  short* wD2T = (short*)alloc((size_t)L * HF * 2);
  float* h_f  = (float*)alloc(SH * 4);
  short* h_b  = (short*)alloc(SH * 2);
  float* y_f  = (float*)alloc(SH * 4);
  short* y_b  = (short*)alloc(SH * 2);
  float* tmpf = (float*)alloc(SH * 4);
  short* qkvb = (short*)alloc(3 * SH * 2);
  float* scf  = (float*)alloc((size_t)S * S * 4);
  short* P_b  = (short*)alloc((size_t)S * S * 2);
  short* attb = (short*)alloc(SH * 2);
  short* ff1b = (short*)alloc((size_t)S * F * 2);
  short* memb = (short*)alloc(SH * 2);
  short* ckb  = (short*)alloc((size_t)L * SH * 2);
  short* cvT  = (short*)alloc((size_t)L * SH * 2);
  float* ftsf = (float*)alloc((size_t)S * TTd * 4);
  float* McB  = (float*)alloc((size_t)VC * 1024 * 4);
  float* bfvB = (float*)alloc((size_t)(VC + 1) * 32 * 4);
  float* termB= (float*)alloc(64);
  unsigned char* bpgB = (unsigned char*)alloc((size_t)2048 * 32);

  short* vtb = ff1b;           // V^T scratch aliases ff1b (disjoint lifetimes)
  short* cvS = (short*)scf;    // cross-V staging aliases scf (pre-decoder only)

  const int ZBIG = 1 << 20;
  const float RSQ = 0.04419417382415922f;  // 1/sqrt(512)

  tconv_k<<<dim3(16, 16, L * 4), 256, 0, stream>>>(eaw, wEAT, H, H);
  tconv_k<<<dim3(16, 16, L * 8), 256, 0, stream>>>(daw, wDAT, H, H);
  tconv_k<<<dim3(64, 16, L), 256, 0, stream>>>(ew1, wE1T, H, F);
  tconv_k<<<dim3(16, 64, L), 256, 0, stream>>>(ew2, wE2T, F, H);
  tconv_k<<<dim3(64, 16, L), 256, 0, stream>>>(dw1, wD1T, H, F);
  tconv_k<<<dim3(16, 64, L), 256, 0, stream>>>(dw2, wD2T, F, H);

  gather_k<<<dim3((unsigned)(SH / 256)), 256, 0, stream>>>(sent, embd, h_f, h_b, y_f, y_b);

  // gemm variants
  auto G_qkv = gemm2<128, 64, true, false, false, false, true>;   // batched qkv -> bf16
  auto G_q1  = gemm2<64, 64, true, false, false, false, true>;    // single proj -> bf16
  auto G_sc  = gemm2<128, 128, false, false, false, true, false>; // scores -> f32
  auto G_pv  = gemm2<64, 64, false, false, false, false, true>;   // PV -> bf16
  auto G_out = gemm2<64, 64, true, false, true, true, false>;     // bias+resid -> f32
  auto G_ff1 = gemm2<128, 128, true, true, false, false, true>;   // bias+relu -> bf16

  dim3 g6464(8, 32, 1), g128(16, 16, 1);

  // ---------------- encoder ----------------
  for (int i = 0; i < L; ++i) {
    G_qkv<<<dim3(8, 16, 3), 256, 0, stream>>>(
        h_b, wEAT + (size_t)i * 4 * HH2, eab + (size_t)i * 4 * H, nullptr, nullptr, qkvb,
        S, H, H, 1.f, ZBIG, 0, HH2, 0, H, SH);
    tb16_k<<<dim3(16, 64, 1), 256, 0, stream>>>(qkvb + 2 * SH, vtb, S, H);
    G_sc<<<g128, 256, 0, stream>>>(
        qkvb, qkvb + SH, nullptr, nullptr, scf, nullptr,
        S, S, H, RSQ, 1, 0, 0, 0, 0, 0);
    softmax_k<<<dim3(S), 256, 0, stream>>>(scf, P_b);
    G_pv<<<g6464, 256, 0, stream>>>(
        P_b, vtb, nullptr, nullptr, nullptr, attb,
        S, H, S, 1.f, 1, 0, 0, 0, 0, 0);
    G_out<<<g6464, 256, 0, stream>>>(
        attb, wEAT + ((size_t)i * 4 + 3) * HH2, eab + ((size_t)i * 4 + 3) * H, h_f, tmpf, nullptr,
        S, H, H, 1.f, 1, 0, 0, 0, 0, 0);
    ln_k<<<dim3(S), 256, 0, stream>>>(tmpf, elnw + (size_t)(i * 2) * H, elnb + (size_t)(i * 2) * H, h_f, h_b);
    G_ff1<<<g128, 256, 0, stream>>>(
        h_b, wE1T + (size_t)i * HF, eb1 + (size_t)i * F, nullptr, nullptr, ff1b,
        S, F, H, 1.f, 1, 0, 0, 0, 0, 0);
    G_out<<<g6464, 256, 0, stream>>>(
        ff1b, wE2T + (size_t)i * HF, eb2 + (size_t)i * H, h_f, tmpf, nullptr,
        S, H, F, 1.f, 1, 0, 0, 0, 0, 0);
    ln_k<<<dim3(S), 256, 0, stream>>>(tmpf, elnw + (size_t)(i * 2 + 1) * H, elnb + (size_t)(i * 2 + 1) * H, h_f, h_b);
  }
  ln_k<<<dim3(S), 256, 0, stream>>>(h_f, enw, enb, tmpf, memb);

  // cross K (j=5) and cross V (j=6) for all layers
  G_qkv<<<dim3(8, 16, L), 256, 0, stream>>>(
      memb, wDAT + 5 * HH2, dab + 5 * H, nullptr, nullptr, ckb,
      S, H, H, 1.f, 1, 8 * HH2, 0, 8 * H, 0, SH);
  G_qkv<<<dim3(8, 16, L), 256, 0, stream>>>(
      memb, wDAT + 6 * HH2, dab + 6 * H, nullptr, nullptr, cvS,
      S, H, H, 1.f, 1, 8 * HH2, 0, 8 * H, 0, SH);
  tb16_k<<<dim3(16, 64, L), 256, 0, stream>>>(cvS, cvT, S, H);

  // ---------------- decoder ----------------
  for (int i = 0; i < L; ++i) {
    G_qkv<<<dim3(8, 16, 3), 256, 0, stream>>>(
        y_b, wDAT + (size_t)i * 8 * HH2, dab + (size_t)i * 8 * H, nullptr, nullptr, qkvb,
        S, H, H, 1.f, ZBIG, 0, HH2, 0, H, SH);
    tb16_k<<<dim3(16, 64, 1), 256, 0, stream>>>(qkvb + 2 * SH, vtb, S, H);
    G_sc<<<g128, 256, 0, stream>>>(
        qkvb, qkvb + SH, nullptr, nullptr, scf, nullptr,
        S, S, H, RSQ, 1, 0, 0, 0, 0, 0);
    softmax_k<<<dim3(S), 256, 0, stream>>>(scf, P_b);
    G_pv<<<g6464, 256, 0, stream>>>(
        P_b, vtb, nullptr, nullptr, nullptr, attb,
        S, H, S, 1.f, 1, 0, 0, 0, 0, 0);
    G_out<<<g6464, 256, 0, stream>>>(
        attb, wDAT + ((size_t)i * 8 + 3) * HH2, dab + ((size_t)i * 8 + 3) * H, y_f, tmpf, nullptr,
        S, H, H, 1.f, 1, 0, 0, 0, 0, 0);
    ln_k<<<dim3(S), 256, 0, stream>>>(tmpf, dlnw + (size_t)(i * 3) * H, dlnb + (size_t)(i * 3) * H, y_f, y_b);
    // cross-attn
    G_q1<<<g6464, 256, 0, stream>>>(
        y_b, wDAT + ((size_t)i * 8 + 4) * HH2, dab + ((size_t)i * 8 + 4) * H, nullptr, nullptr, qkvb,
        S, H, H, 1.f, ZBIG, 0, HH2, 0, H, SH);
    G_sc<<<g128, 256, 0, stream>>>(
        qkvb, ckb + (size_t)i * SH, nullptr, nullptr, scf, nullptr,
        S, S, H, RSQ, 1, 0, 0, 0, 0, 0);
    softmax_k<<<dim3(S), 256, 0, stream>>>(scf, P_b);
    G_pv<<<g6464, 256, 0, stream>>>(
        P_b, cvT + (size_t)i * SH, nullptr, nullptr, nullptr, attb,
        S, H, S, 1.f, 1, 0, 0, 0, 0, 0);
    G_out<<<g6464, 256, 0, stream>>>(
        attb, wDAT + ((size_t)i * 8 + 7) * HH2, dab + ((size_t)i * 8 + 7) * H, y_f, tmpf, nullptr,
        S, H, H, 1.f, 1, 0, 0, 0, 0, 0);
    ln_k<<<dim3(S), 256, 0, stream>>>(tmpf, dlnw + (size_t)(i * 3 + 1) * H, dlnb + (size_t)(i * 3 + 1) * H, y_f, y_b);
    // FFN
    G_ff1<<<g128, 256, 0, stream>>>(
        y_b, wD1T + (size_t)i * HF, db1 + (size_t)i * F, nullptr, nullptr, ff1b,
        S, F, H, 1.f, 1, 0, 0, 0, 0, 0);
    G_out<<<g6464, 256, 0, stream>>>(
        ff1b, wD2T + (size_t)i * HF, db2 + (size_t)i * H, y_f, tmpf, nullptr,
        S, H, F, 1.f, 1, 0, 0, 0, 0, 0);
    ln_k<<<dim3(S), 256, 0, stream>>>(tmpf, dlnw + (size_t)(i * 3 + 2) * H, dlnb + (size_t)(i * 3 + 2) * H, y_f, y_b);
  }
  // final norm + feats + parallel viterbi
  ln_k<<<dim3(S), 256, 0, stream>>>(y_f, dnw, dnb, tmpf, memb);
  feats_k<<<dim3(S / 8), 256, 0, stream>>>(tmpf, h2tw, h2tb, ftsf);
  float* outF = (float*)d_out;
  vit_p1<<<dim3(VC), 256, 0, stream>>>(ftsf, trns, McB);
  vit_p2<<<dim3(1), 64, 0, stream>>>(McB, trns, bfvB, termB, outF);
  vit_p3<<<dim3(VC), 64, 0, stream>>>(ftsf, trns, bfvB, bpgB);
  vit_p4<<<dim3(1), 64, 0, stream>>>(bpgB, termB, outF);
}

// Round 4
// 1875.229 us; speedup vs baseline: 3.3642x; 1.1661x over previous
//
#include <hip/hip_runtime.h>
#include <cstdint>

#define SS 2048
#define HHd 512
#define FFd 2048
#define TTd 32
#define LLd 6
#define VW 16
#define VC 128

typedef float f32x4 __attribute__((ext_vector_type(4)));
typedef __bf16 bf16x8 __attribute__((ext_vector_type(8)));
typedef short short8v __attribute__((ext_vector_type(8)));
typedef short short4v __attribute__((ext_vector_type(4)));

__device__ __forceinline__ short f2b(float f) {
  unsigned u = __builtin_bit_cast(unsigned, f);
  u += 0x7fffu + ((u >> 16) & 1u);
  return (short)(u >> 16);
}

typedef const __attribute__((address_space(1))) void gv_t;
typedef __attribute__((address_space(3))) void lv_t;
__device__ __forceinline__ void gload16(const void* g, void* l) {
  __builtin_amdgcn_global_load_lds((gv_t*)g, (lv_t*)l, 16, 0, 0);
}

// ------------------------------ GEMM (all-TB, BK=64, swizzled LDS) ------------------------------
// C[M,N] = A[M,K] @ B^T, B is [N,K] row-major bf16.
// LDS rows = 64 shorts (128B, 8 16B-slots); phys slot = logical slot ^ (row&7).
// Staging: gload16 writes linearly; global source pre-swizzled: col16 = (l&7)^((l>>3)&7).
// z-batching: B += (z/zdiv)*bs1 + (z%zdiv)*bs2; bias likewise; C += z*cStr; k-offset = z*kzS (split-K).
template<int BMt, int BNt, bool BIAS, bool RELU, bool RESID, bool OUTF, bool OUTB>
__global__ __launch_bounds__(256) void gemm3(
    const short* __restrict__ A, const short* __restrict__ Bb,
    const float* __restrict__ biasb, const float* __restrict__ resid,
    float* __restrict__ Cfb, short* __restrict__ Cbb,
    int M, int N, int K, int lda, int ldb, int kzS, float scale,
    int zdiv, long bs1, long bs2, int bb1, int bb2, long cStr)
{
  constexpr int MR = BMt / 32, NR = BNt / 32;
  constexpr int WMt = BMt / 2, WNt = BNt / 2;
  constexpr int ACALLS = BMt / 8;
  constexpr int TOT = (BMt + BNt) / 8;
  constexpr int CPW = TOT / 4;

  const int z = blockIdx.z;
  const short* Bp = Bb + (long)(z / zdiv) * bs1 + (long)(z % zdiv) * bs2;
  const float* bias = BIAS ? (biasb + (z / zdiv) * bb1 + (z % zdiv) * bb2) : nullptr;
  const int kz = z * kzS;

  const int m0 = blockIdx.y * BMt;
  const int n0 = blockIdx.x * BNt;

  __shared__ __align__(16) short As[BMt * 64];
  __shared__ __align__(16) short Bs[BNt * 64];

  const int tid = threadIdx.x;
  const int lane = tid & 63;
  const int w = tid >> 6;

  const short* srcs[CPW];
  short* ldss[CPW];
  {
    const int rl8 = lane >> 3;
    const int c16 = (lane & 7) ^ rl8;
#pragma unroll
    for (int c = 0; c < CPW; ++c) {
      int q = w * CPW + c;
      if (q < ACALLS) {
        int row = q * 8 + rl8;
        srcs[c] = A + (long)(m0 + row) * lda + kz + c16 * 8;
        ldss[c] = &As[q * 512];
      } else {
        int row = (q - ACALLS) * 8 + rl8;
        srcs[c] = Bp + (long)(n0 + row) * ldb + kz + c16 * 8;
        ldss[c] = &Bs[(q - ACALLS) * 512];
      }
    }
  }

  const int lrow = lane & 15;
  const int slotb = lane >> 4;          // 0..3
  const int wm = (w >> 1) * WMt, wn = (w & 1) * WNt;

  f32x4 acc[MR][NR] = {};

  for (int k0 = 0; k0 < K; k0 += 64) {
#pragma unroll
    for (int c = 0; c < CPW; ++c) gload16(srcs[c], ldss[c]);
#pragma unroll
    for (int c = 0; c < CPW; ++c) srcs[c] += 64;
    __syncthreads();
#pragma unroll
    for (int s = 0; s < 2; ++s) {
      bf16x8 af[MR], bfv[NR];
#pragma unroll
      for (int f = 0; f < MR; ++f) {
        int row = wm + f * 16 + lrow;
        int phys = (slotb + s * 4) ^ (row & 7);
        af[f] = *(const bf16x8*)&As[row * 64 + phys * 8];
      }
#pragma unroll
      for (int f = 0; f < NR; ++f) {
        int row = wn + f * 16 + lrow;
        int phys = (slotb + s * 4) ^ (row & 7);
        bfv[f] = *(const bf16x8*)&Bs[row * 64 + phys * 8];
      }
#pragma unroll
      for (int i = 0; i < MR; ++i)
#pragma unroll
        for (int j = 0; j < NR; ++j)
          acc[i][j] = __builtin_amdgcn_mfma_f32_16x16x32_bf16(af[i], bfv[j], acc[i][j], 0, 0, 0);
    }
    __syncthreads();
  }

  float* Cf = OUTF ? (Cfb + (long)z * cStr) : nullptr;
  short* Cb = OUTB ? (Cbb + (long)z * cStr) : nullptr;
  const int crow = (lane >> 4) * 4;
  const int ccol = lane & 15;
#pragma unroll
  for (int i = 0; i < MR; ++i) {
#pragma unroll
    for (int j = 0; j < NR; ++j) {
      int gc = n0 + wn + j * 16 + ccol;
      float bv = BIAS ? bias[gc] : 0.f;
#pragma unroll
      for (int r = 0; r < 4; ++r) {
        int gr = m0 + wm + i * 16 + crow + r;
        long off = (long)gr * N + gc;
        float v = acc[i][j][r] * scale + bv;
        if (RESID) v += resid[off];
        if (RELU) v = v > 0.f ? v : 0.f;
        if (OUTF) Cf[off] = v;
        if (OUTB) Cb[off] = f2b(v);
      }
    }
  }
}

// ---------------- split-K=4 reduce -> bf16 ----------------
__global__ __launch_bounds__(256) void r4b_k(const float* __restrict__ pb, short* __restrict__ out) {
  const long SH = (long)SS * HHd;
  long i = ((long)blockIdx.x * 256 + threadIdx.x) * 4;
  f32x4 a = *(const f32x4*)(pb + i);
  f32x4 b = *(const f32x4*)(pb + SH + i);
  f32x4 c = *(const f32x4*)(pb + 2 * SH + i);
  f32x4 d = *(const f32x4*)(pb + 3 * SH + i);
  f32x4 s = (a + b) + (c + d);
  short4v o;
  o[0] = f2b(s[0]); o[1] = f2b(s[1]); o[2] = f2b(s[2]); o[3] = f2b(s[3]);
  *(short4v*)(out + i) = o;
}

// ---------------- split-K=4 reduce + bias + resid + LayerNorm ----------------
__global__ __launch_bounds__(256) void r4ln_k(const float* __restrict__ pb,
                                              const float* __restrict__ bias,
                                              const float* __restrict__ resid,
                                              const float* __restrict__ w, const float* __restrict__ b,
                                              float* __restrict__ Yf, short* __restrict__ Yb) {
  const long SH = (long)SS * HHd;
  const int row = blockIdx.x, tid = threadIdx.x;
  long base = (long)row * HHd;
  float x0 = bias[tid] + resid[base + tid];
  float x1 = bias[tid + 256] + resid[base + tid + 256];
#pragma unroll
  for (int sk = 0; sk < 4; ++sk) {
    x0 += pb[sk * SH + base + tid];
    x1 += pb[sk * SH + base + tid + 256];
  }
  float s = x0 + x1;
#pragma unroll
  for (int o = 32; o; o >>= 1) s += __shfl_xor(s, o);
  __shared__ float r1[4], r2[4];
  if ((tid & 63) == 0) r1[tid >> 6] = s;
  __syncthreads();
  float mean = (r1[0] + r1[1] + r1[2] + r1[3]) * (1.f / HHd);
  float d0 = x0 - mean, d1 = x1 - mean;
  float q = d0 * d0 + d1 * d1;
#pragma unroll
  for (int o = 32; o; o >>= 1) q += __shfl_xor(q, o);
  if ((tid & 63) == 0) r2[tid >> 6] = q;
  __syncthreads();
  float var = (r2[0] + r2[1] + r2[2] + r2[3]) * (1.f / HHd);
  float rs = rsqrtf(var + 1e-5f);
  float o0 = d0 * rs * w[tid] + b[tid];
  float o1 = d1 * rs * w[tid + 256] + b[tid + 256];
  Yf[base + tid] = o0; Yf[base + tid + 256] = o1;
  Yb[base + tid] = f2b(o0); Yb[base + tid + 256] = f2b(o1);
}

// ---------------- f32 [K,N] -> bf16 [N,K] transpose-convert (batched z) ----------------
__global__ __launch_bounds__(256) void tconv_k(const float* __restrict__ in, short* __restrict__ out,
                                               int K, int N) {
  __shared__ float t[32][33];
  long zo = (long)blockIdx.z * K * N;
  int n0 = blockIdx.x * 32, k0 = blockIdx.y * 32;
  int tx = threadIdx.x & 31, ty = threadIdx.x >> 5;
#pragma unroll
  for (int i = 0; i < 4; ++i)
    t[ty + i * 8][tx] = in[zo + (long)(k0 + ty + i * 8) * N + n0 + tx];
  __syncthreads();
#pragma unroll
  for (int i = 0; i < 4; ++i)
    out[zo + (long)(n0 + ty + i * 8) * K + k0 + tx] = f2b(t[tx][ty + i * 8]);
}

// ---------------- bf16 [R,C] -> bf16 [C,R] transpose (batched z, separate strides) ----------------
__global__ __launch_bounds__(256) void tb16_k(const short* __restrict__ in, short* __restrict__ out,
                                              int R, int C, long inStride, long outStride) {
  __shared__ short t[32][34];
  const short* inp = in + (long)blockIdx.z * inStride;
  short* outp = out + (long)blockIdx.z * outStride;
  int c0 = blockIdx.x * 32, r0 = blockIdx.y * 32;
  int tx = threadIdx.x & 31, ty = threadIdx.x >> 5;
#pragma unroll
  for (int i = 0; i < 4; ++i)
    t[ty + i * 8][tx] = inp[(long)(r0 + ty + i * 8) * C + c0 + tx];
  __syncthreads();
#pragma unroll
  for (int i = 0; i < 4; ++i)
    outp[(long)(c0 + ty + i * 8) * R + r0 + tx] = t[tx][ty + i * 8];
}

// ------------------------------ softmax over rows of [SS,SS] ------------------------------
__global__ __launch_bounds__(256) void softmax_k(const float* __restrict__ Sc, short* __restrict__ P) {
  const int row = blockIdx.x;
  const float* src = Sc + (long)row * SS;
  const int tid = threadIdx.x;
  float vals[8];
  float mx = -3.0e38f;
#pragma unroll
  for (int i = 0; i < 8; ++i) {
    vals[i] = src[tid + i * 256];
    mx = fmaxf(mx, vals[i]);
  }
#pragma unroll
  for (int o = 32; o; o >>= 1) mx = fmaxf(mx, __shfl_xor(mx, o));
  __shared__ float r1[4], r2[4];
  if ((tid & 63) == 0) r1[tid >> 6] = mx;
  __syncthreads();
  mx = fmaxf(fmaxf(r1[0], r1[1]), fmaxf(r1[2], r1[3]));
  float sum = 0.f;
#pragma unroll
  for (int i = 0; i < 8; ++i) { vals[i] = __expf(vals[i] - mx); sum += vals[i]; }
#pragma unroll
  for (int o = 32; o; o >>= 1) sum += __shfl_xor(sum, o);
  if ((tid & 63) == 0) r2[tid >> 6] = sum;
  __syncthreads();
  sum = r2[0] + r2[1] + r2[2] + r2[3];
  float inv = 1.0f / sum;
  short* dst = P + (long)row * SS;
#pragma unroll
  for (int i = 0; i < 8; ++i) dst[tid + i * 256] = f2b(vals[i] * inv);
}

// ------------------------------ LayerNorm over rows of [SS,HHd] ------------------------------
__global__ __launch_bounds__(256) void ln_k(const float* __restrict__ X, const float* __restrict__ w,
                                            const float* __restrict__ b, float* __restrict__ Yf,
                                            short* __restrict__ Yb) {
  const int row = blockIdx.x;
  const int tid = threadIdx.x;
  const float* src = X + (long)row * HHd;
  float x0 = src[tid], x1 = src[tid + 256];
  float s = x0 + x1;
#pragma unroll
  for (int o = 32; o; o >>= 1) s += __shfl_xor(s, o);
  __shared__ float r1[4], r2[4];
  if ((tid & 63) == 0) r1[tid >> 6] = s;
  __syncthreads();
  float mean = (r1[0] + r1[1] + r1[2] + r1[3]) * (1.f / HHd);
  float d0 = x0 - mean, d1 = x1 - mean;
  float q = d0 * d0 + d1 * d1;
#pragma unroll
  for (int o = 32; o; o >>= 1) q += __shfl_xor(q, o);
  if ((tid & 63) == 0) r2[tid >> 6] = q;
  __syncthreads();
  float var = (r2[0] + r2[1] + r2[2] + r2[3]) * (1.f / HHd);
  float rs = rsqrtf(var + 1e-5f);
  float o0 = d0 * rs * w[tid] + b[tid];
  float o1 = d1 * rs * w[tid + 256] + b[tid + 256];
  long base = (long)row * HHd;
  Yf[base + tid] = o0; Yf[base + tid + 256] = o1;
  Yb[base + tid] = f2b(o0); Yb[base + tid + 256] = f2b(o1);
}

// ------------------------------ embedding gather ------------------------------
__global__ __launch_bounds__(256) void gather_k(const int* __restrict__ sent, const float* __restrict__ emb,
                                                float* __restrict__ hf, short* __restrict__ hb,
                                                float* __restrict__ yf, short* __restrict__ yb) {
  long i = (long)blockIdx.x * 256 + threadIdx.x;
  int s = (int)(i >> 9);
  int hcol = (int)(i & 511);
  float v = emb[(long)sent[s] * HHd + hcol];
  short bb = f2b(v);
  hf[i] = v; yf[i] = v; hb[i] = bb; yb[i] = bb;
}

// ------------------------------ feats: [SS,HHd] @ [HHd,TTd] + b (f32) ------------------------------
__global__ __launch_bounds__(256) void feats_k(const float* __restrict__ Y, const float* __restrict__ W,
                                               const float* __restrict__ b, float* __restrict__ feats) {
  __shared__ float ys[8 * HHd];
  const int row0 = blockIdx.x * 8;
  for (int i = threadIdx.x; i < 8 * HHd; i += 256) ys[i] = Y[(long)row0 * HHd + i];
  __syncthreads();
  const int n = threadIdx.x & 31, r = threadIdx.x >> 5;
  float acc = b[n];
  const float* yr = &ys[r * HHd];
  for (int k = 0; k < HHd; ++k) acc = fmaf(yr[k], W[k * TTd + n], acc);
  feats[(long)(row0 + r) * TTd + n] = acc;
}

// ============================== Parallel Viterbi (VC chunks x VW steps) ==============================
__global__ __launch_bounds__(256) void vit_p1(const float* __restrict__ feats,
                                              const float* __restrict__ trans,
                                              float* __restrict__ Mc) {
  __shared__ float trS[1024];
  __shared__ float fS[VW * 32];
  __shared__ float Ga[32 * 33], Gb[32 * 33];
  const int c = blockIdx.x, tid = threadIdx.x;
  for (int i = tid; i < 1024; i += 256) trS[i] = trans[i];
  for (int i = tid; i < VW * 32; i += 256) fS[i] = feats[c * VW * 32 + i];
  __syncthreads();
  for (int i = tid; i < 1024; i += 256) {
    int n = i >> 5, q = i & 31;
    Ga[n * 33 + q] = trS[i] + fS[n];
  }
  __syncthreads();
  float* G = Ga;
  float* Gn = Gb;
  const int q = tid & 31, nb = (tid >> 5) * 4;
  for (int s = 1; s < VW; ++s) {
    float m0 = -3.0e38f, m1 = -3.0e38f, m2 = -3.0e38f, m3 = -3.0e38f;
    for (int pp = 0; pp < 32; ++pp) {
      float g = G[pp * 33 + q];
      m0 = fmaxf(m0, trS[(nb + 0) * 32 + pp] + g);
      m1 = fmaxf(m1, trS[(nb + 1) * 32 + pp] + g);
      m2 = fmaxf(m2, trS[(nb + 2) * 32 + pp] + g);
      m3 = fmaxf(m3, trS[(nb + 3) * 32 + pp] + g);
    }
    Gn[(nb + 0) * 33 + q] = m0 + fS[s * 32 + nb + 0];
    Gn[(nb + 1) * 33 + q] = m1 + fS[s * 32 + nb + 1];
    Gn[(nb + 2) * 33 + q] = m2 + fS[s * 32 + nb + 2];
    Gn[(nb + 3) * 33 + q] = m3 + fS[s * 32 + nb + 3];
    __syncthreads();
    float* t = G; G = Gn; Gn = t;
  }
  for (int i = tid; i < 1024; i += 256) Mc[c * 1024 + i] = G[(i >> 5) * 33 + (i & 31)];
}

__global__ __launch_bounds__(64) void vit_p2(const float* __restrict__ Mc,
                                             const float* __restrict__ trans,
                                             float* __restrict__ bfv,
                                             float* __restrict__ term,
                                             float* __restrict__ out) {
  const int lane = threadIdx.x, n = lane & 31, h = lane >> 5, p0 = h << 4;
  float fv = (n == 30) ? 0.f : -10000.f;
  if (lane < 32) bfv[lane] = fv;
  f32x4 A0, A1, A2, A3;
  {
    const float* M = Mc + n * 32 + p0;
    A0 = *(const f32x4*)(M); A1 = *(const f32x4*)(M + 4);
    A2 = *(const f32x4*)(M + 8); A3 = *(const f32x4*)(M + 12);
  }
  for (int c = 0; c < VC; ++c) {
    f32x4 B0 = A0, B1 = A1, B2 = A2, B3 = A3;
    if (c + 1 < VC) {
      const float* M = Mc + (c + 1) * 1024 + n * 32 + p0;
      B0 = *(const f32x4*)(M); B1 = *(const f32x4*)(M + 4);
      B2 = *(const f32x4*)(M + 8); B3 = *(const f32x4*)(M + 12);
    }
    float cnd[16];
#pragma unroll
    for (int j = 0; j < 16; ++j) {
      float mv = (j < 4) ? A0[j] : (j < 8) ? A1[j - 4] : (j < 12) ? A2[j - 8] : A3[j - 12];
      cnd[j] = __shfl(fv, p0 + j) + mv;
    }
    float t8[8];
#pragma unroll
    for (int j = 0; j < 8; ++j) t8[j] = fmaxf(cnd[2 * j], cnd[2 * j + 1]);
    float t4[4];
#pragma unroll
    for (int j = 0; j < 4; ++j) t4[j] = fmaxf(t8[2 * j], t8[2 * j + 1]);
    float bv = fmaxf(fmaxf(t4[0], t4[1]), fmaxf(t4[2], t4[3]));
    bv = fmaxf(bv, __shfl_xor(bv, 32));
    fv = bv;
    if (lane < 32) bfv[(c + 1) * 32 + n] = fv;
    A0 = B0; A1 = B1; A2 = B2; A3 = B3;
  }
  float v = fv + trans[31 * 32 + n];
  int idx = n;
#pragma unroll
  for (int o = 16; o; o >>= 1) {
    float ov = __shfl_xor(v, o);
    int oi = __shfl_xor(idx, o);
    if (ov > v || (ov == v && oi < idx)) { v = ov; idx = oi; }
  }
  if (lane == 0) { out[0] = v; term[0] = (float)idx; }
}

__global__ __launch_bounds__(64) void vit_p3(const float* __restrict__ feats,
                                             const float* __restrict__ trans,
                                             const float* __restrict__ bfv,
                                             unsigned char* __restrict__ bp) {
  const int c = blockIdx.x, lane = threadIdx.x, n = lane & 31, h = lane >> 5, p0 = h << 4;
  float tr[16];
#pragma unroll
  for (int j = 0; j < 16; ++j) tr[j] = trans[n * 32 + p0 + j];
  float fv = bfv[c * 32 + n];
  float ft[VW];
  for (int s = 0; s < VW; ++s) ft[s] = feats[(c * VW + s) * 32 + n];
  for (int s = 0; s < VW; ++s) {
    float cd[16];
#pragma unroll
    for (int j = 0; j < 16; ++j) cd[j] = __shfl(fv, p0 + j) + tr[j];
    float v8[8]; int i8a[8];
#pragma unroll
    for (int j = 0; j < 8; ++j) {
      bool g = cd[2 * j + 1] > cd[2 * j];
      v8[j] = g ? cd[2 * j + 1] : cd[2 * j];
      i8a[j] = g ? 2 * j + 1 : 2 * j;
    }
    float v4[4]; int i4a[4];
#pragma unroll
    for (int j = 0; j < 4; ++j) {
      bool g = v8[2 * j + 1] > v8[2 * j];
      v4[j] = g ? v8[2 * j + 1] : v8[2 * j];
      i4a[j] = g ? i8a[2 * j + 1] : i8a[2 * j];
    }
    float v2[2]; int i2a[2];
#pragma unroll
    for (int j = 0; j < 2; ++j) {
      bool g = v4[2 * j + 1] > v4[2 * j];
      v2[j] = g ? v4[2 * j + 1] : v4[2 * j];
      i2a[j] = g ? i4a[2 * j + 1] : i4a[2 * j];
    }
    bool g1 = v2[1] > v2[0];
    float bv = g1 ? v2[1] : v2[0];
    int bi = p0 + (g1 ? i2a[1] : i2a[0]);
    float ov = __shfl_xor(bv, 32);
    int oi = __shfl_xor(bi, 32);
    bool takeo = h ? (ov >= bv) : (ov > bv);
    float m = takeo ? ov : bv;
    int mi = takeo ? oi : bi;
    if (!h) bp[(c * VW + s) * 32 + n] = (unsigned char)mi;
    fv = m + ft[s];
  }
}

__global__ __launch_bounds__(VC) void vit_p4(const unsigned char* __restrict__ bp,
                                             const float* __restrict__ term,
                                             float* __restrict__ out) {
  __shared__ unsigned char GsL[VC * 32];
  __shared__ unsigned char bnd[VC];
  const int lane = threadIdx.x;  // chunk id, 0..VC-1
  unsigned char g[32];
#pragma unroll
  for (int j = 0; j < 32; ++j) g[j] = (unsigned char)j;
  for (int s = VW - 1; s >= 0; --s) {
    const unsigned char* rowp = bp + (lane * VW + s) * 32;
#pragma unroll
    for (int j = 0; j < 32; ++j) g[j] = rowp[g[j]];
  }
#pragma unroll
  for (int j = 0; j < 32; ++j) GsL[lane * 32 + j] = g[j];
  __syncthreads();
  if (lane == 0) {
    bnd[VC - 1] = (unsigned char)(int)term[0];
    for (int cc = VC - 1; cc >= 1; --cc) bnd[cc - 1] = GsL[cc * 32 + bnd[cc]];
  }
  __syncthreads();
  int x = bnd[lane];
  out[1 + lane * VW + VW - 1] = (float)x;
  for (int k = VW - 2; k >= 0; --k) {
    x = bp[(lane * VW + k + 1) * 32 + x];
    out[1 + lane * VW + k] = (float)x;
  }
}

// ------------------------------ host ------------------------------
extern "C" void kernel_launch(void* const* d_in, const int* in_sizes, int n_in,
                              void* d_out, int out_size, void* d_ws, size_t ws_size,
                              hipStream_t stream) {
  (void)in_sizes; (void)n_in; (void)out_size; (void)ws_size;
  const int H = HHd, F = FFd, S = SS, L = LLd;
  const long HH2 = (long)H * H;
  const long SH = (long)S * H;
  const long HF = (long)H * F;

  const int*   sent = (const int*)d_in[0];
  const float* embd = (const float*)d_in[1];
  const float* eaw  = (const float*)d_in[2];
  const float* eab  = (const float*)d_in[3];
  const float* ew1  = (const float*)d_in[4];
  const float* eb1  = (const float*)d_in[5];
  const float* ew2  = (const float*)d_in[6];
  const float* eb2  = (const float*)d_in[7];
  const float* elnw = (const float*)d_in[8];
  const float* elnb = (const float*)d_in[9];
  const float* daw  = (const float*)d_in[10];
  const float* dab  = (const float*)d_in[11];
  const float* dw1  = (const float*)d_in[12];
  const float* db1  = (const float*)d_in[13];
  const float* dw2  = (const float*)d_in[14];
  const float* db2  = (const float*)d_in[15];
  const float* dlnw = (const float*)d_in[16];
  const float* dlnb = (const float*)d_in[17];
  const float* enw  = (const float*)d_in[18];
  const float* enb  = (const float*)d_in[19];
  const float* dnw  = (const float*)d_in[20];
  const float* dnb  = (const float*)d_in[21];
  const float* h2tw = (const float*)d_in[22];
  const float* h2tb = (const float*)d_in[23];
  const float* trns = (const float*)d_in[24];

  char* p = (char*)d_ws;
  auto alloc = [&](size_t bytes) -> char* {
    char* r = p;
    p += (bytes + 255) & ~(size_t)255;
    return r;
  };
  short* wEAT = (short*)alloc((size_t)L * 4 * HH2 * 2);
  short* wDAT = (short*)alloc((size_t)L * 8 * HH2 * 2);
  short* wE1T = (short*)alloc((size_t)L * HF * 2);
  short* wE2T = (short*)alloc((size_t)L * HF * 2);
  short* wD1T = (short*)alloc((size_t)L * HF * 2);
  short* wD2T = (short*)alloc((size_t)L * HF * 2);
  float* h_f  = (float*)alloc(SH * 4);
  short* h_b  = (short*)alloc(SH * 2);
  float* y_f  = (float*)alloc(SH * 4);
  short* y_b  = (short*)alloc(SH * 2);
  float* tmpf = (float*)alloc(SH * 4);
  short* qkvb = (short*)alloc(3 * SH * 2);
  float* scf  = (float*)alloc((size_t)S * S * 4);   // scores AND split-K partial buffer (16MB)
  short* P_b  = (short*)alloc((size_t)S * S * 2);
  short* attb = (short*)alloc(SH * 2);
  short* ff1b = (short*)alloc((size_t)S * F * 2);
  short* memb = (short*)alloc(SH * 2);
  short* ckvA = (short*)alloc((size_t)2 * L * SH * 2);  // interleaved cross K/V per layer
  short* cvT  = (short*)alloc((size_t)L * SH * 2);
  float* ftsf = (float*)alloc((size_t)S * TTd * 4);
  float* McB  = (float*)alloc((size_t)VC * 1024 * 4);
  float* bfvB = (float*)alloc((size_t)(VC + 1) * 32 * 4);
  float* termB= (float*)alloc(64);
  unsigned char* bpgB = (unsigned char*)alloc((size_t)2048 * 32);

  short* vtb = ff1b;           // V^T scratch aliases ff1b (disjoint lifetimes)

  const int ZBIG = 1 << 20;
  const float RSQ = 0.04419417382415922f;  // 1/sqrt(512)

  tconv_k<<<dim3(16, 16, L * 4), 256, 0, stream>>>(eaw, wEAT, H, H);
  tconv_k<<<dim3(16, 16, L * 8), 256, 0, stream>>>(daw, wDAT, H, H);
  tconv_k<<<dim3(64, 16, L), 256, 0, stream>>>(ew1, wE1T, H, F);
  tconv_k<<<dim3(16, 64, L), 256, 0, stream>>>(ew2, wE2T, F, H);
  tconv_k<<<dim3(64, 16, L), 256, 0, stream>>>(dw1, wD1T, H, F);
  tconv_k<<<dim3(16, 64, L), 256, 0, stream>>>(dw2, wD2T, F, H);

  gather_k<<<dim3((unsigned)(SH / 256)), 256, 0, stream>>>(sent, embd, h_f, h_b, y_f, y_b);

  // gemm variants
  auto G_qkv = gemm3<128, 128, true, false, false, false, true>;  // batched proj -> bf16 (fat tile)
  auto G_q1  = gemm3<64, 64, true, false, false, false, true>;    // single proj -> bf16
  auto G_sc  = gemm3<128, 128, false, false, false, true, false>; // scores -> f32
  auto G_spl = gemm3<128, 128, false, false, false, true, false>; // split-K partials -> f32
  auto G_out = gemm3<64, 64, true, false, true, true, false>;     // bias+resid -> f32
  auto G_ff1 = gemm3<128, 128, true, true, false, false, true>;   // bias+relu -> bf16

  dim3 gQKV(4, 16, 3), gSC(16, 16, 1), gSPL(4, 16, 4), g64(8, 32, 1), gFF1(16, 16, 1);

  // ---------------- encoder ----------------
  for (int i = 0; i < L; ++i) {
    G_qkv<<<gQKV, 256, 0, stream>>>(
        h_b, wEAT + (size_t)i * 4 * HH2, eab + (size_t)i * 4 * H, nullptr, nullptr, qkvb,
        S, H, H, H, H, 0, 1.f, ZBIG, 0, HH2, 0, H, SH);
    tb16_k<<<dim3(16, 64, 1), 256, 0, stream>>>(qkvb + 2 * SH, vtb, S, H, 0, 0);
    G_sc<<<gSC, 256, 0, stream>>>(
        qkvb, qkvb + SH, nullptr, nullptr, scf, nullptr,
        S, S, H, H, H, 0, RSQ, 1, 0, 0, 0, 0, 0);
    softmax_k<<<dim3(S), 256, 0, stream>>>(scf, P_b);
    G_spl<<<gSPL, 256, 0, stream>>>(
        P_b, vtb, nullptr, nullptr, scf, nullptr,
        S, H, S / 4, S, S, S / 4, 1.f, 1, 0, 0, 0, 0, SH);
    r4b_k<<<dim3(1024), 256, 0, stream>>>(scf, attb);
    G_out<<<g64, 256, 0, stream>>>(
        attb, wEAT + ((size_t)i * 4 + 3) * HH2, eab + ((size_t)i * 4 + 3) * H, h_f, tmpf, nullptr,
        S, H, H, H, H, 0, 1.f, 1, 0, 0, 0, 0, 0);
    ln_k<<<dim3(S), 256, 0, stream>>>(tmpf, elnw + (size_t)(i * 2) * H, elnb + (size_t)(i * 2) * H, h_f, h_b);
    G_ff1<<<gFF1, 256, 0, stream>>>(
        h_b, wE1T + (size_t)i * HF, eb1 + (size_t)i * F, nullptr, nullptr, ff1b,
        S, F, H, H, H, 0, 1.f, 1, 0, 0, 0, 0, 0);
    G_spl<<<gSPL, 256, 0, stream>>>(
        ff1b, wE2T + (size_t)i * HF, nullptr, nullptr, scf, nullptr,
        S, H, F / 4, F, F, F / 4, 1.f, 1, 0, 0, 0, 0, SH);
    r4ln_k<<<dim3(S), 256, 0, stream>>>(scf, eb2 + (size_t)i * H, h_f,
        elnw + (size_t)(i * 2 + 1) * H, elnb + (size_t)(i * 2 + 1) * H, h_f, h_b);
  }
  ln_k<<<dim3(S), 256, 0, stream>>>(h_f, enw, enb, tmpf, memb);

  // cross K (j=5) and V (j=6) for all layers in one dispatch: z=2*layer + {0:K,1:V}
  G_qkv<<<dim3(4, 16, 2 * L), 256, 0, stream>>>(
      memb, wDAT + 5 * HH2, dab + 5 * H, nullptr, nullptr, ckvA,
      S, H, H, H, H, 0, 1.f, 2, 8 * HH2, HH2, 8 * H, H, SH);
  tb16_k<<<dim3(16, 64, L), 256, 0, stream>>>(ckvA + SH, cvT, S, H, 2 * SH, SH);

  // ---------------- decoder ----------------
  for (int i = 0; i < L; ++i) {
    G_qkv<<<gQKV, 256, 0, stream>>>(
        y_b, wDAT + (size_t)i * 8 * HH2, dab + (size_t)i * 8 * H, nullptr, nullptr, qkvb,
        S, H, H, H, H, 0, 1.f, ZBIG, 0, HH2, 0, H, SH);
    tb16_k<<<dim3(16, 64, 1), 256, 0, stream>>>(qkvb + 2 * SH, vtb, S, H, 0, 0);
    G_sc<<<gSC, 256, 0, stream>>>(
        qkvb, qkvb + SH, nullptr, nullptr, scf, nullptr,
        S, S, H, H, H, 0, RSQ, 1, 0, 0, 0, 0, 0);
    softmax_k<<<dim3(S), 256, 0, stream>>>(scf, P_b);
    G_spl<<<gSPL, 256, 0, stream>>>(
        P_b, vtb, nullptr, nullptr, scf, nullptr,
        S, H, S / 4, S, S, S / 4, 1.f, 1, 0, 0, 0, 0, SH);
    r4b_k<<<dim3(1024), 256, 0, stream>>>(scf, attb);
    G_out<<<g64, 256, 0, stream>>>(
        attb, wDAT + ((size_t)i * 8 + 3) * HH2, dab + ((size_t)i * 8 + 3) * H, y_f, tmpf, nullptr,
        S, H, H, H, H, 0, 1.f, 1, 0, 0, 0, 0, 0);
    ln_k<<<dim3(S), 256, 0, stream>>>(tmpf, dlnw + (size_t)(i * 3) * H, dlnb + (size_t)(i * 3) * H, y_f, y_b);
    // cross-attn
    G_q1<<<g64, 256, 0, stream>>>(
        y_b, wDAT + ((size_t)i * 8 + 4) * HH2, dab + ((size_t)i * 8 + 4) * H, nullptr, nullptr, qkvb,
        S, H, H, H, H, 0, 1.f, ZBIG, 0, 0, 0, 0, 0);
    G_sc<<<gSC, 256, 0, stream>>>(
        qkvb, ckvA + (size_t)(2 * i) * SH, nullptr, nullptr, scf, nullptr,
        S, S, H, H, H, 0, RSQ, 1, 0, 0, 0, 0, 0);
    softmax_k<<<dim3(S), 256, 0, stream>>>(scf, P_b);
    G_spl<<<gSPL, 256, 0, stream>>>(
        P_b, cvT + (size_t)i * SH, nullptr, nullptr, scf, nullptr,
        S, H, S / 4, S, S, S / 4, 1.f, 1, 0, 0, 0, 0, SH);
    r4b_k<<<dim3(1024), 256, 0, stream>>>(scf, attb);
    G_out<<<g64, 256, 0, stream>>>(
        attb, wDAT + ((size_t)i * 8 + 7) * HH2, dab + ((size_t)i * 8 + 7) * H, y_f, tmpf, nullptr,
        S, H, H, H, H, 0, 1.f, 1, 0, 0, 0, 0, 0);
    ln_k<<<dim3(S), 256, 0, stream>>>(tmpf, dlnw + (size_t)(i * 3 + 1) * H, dlnb + (size_t)(i * 3 + 1) * H, y_f, y_b);
    // FFN
    G_ff1<<<gFF1, 256, 0, stream>>>(
        y_b, wD1T + (size_t)i * HF, db1 + (size_t)i * F, nullptr, nullptr, ff1b,
        S, F, H, H, H, 0, 1.f, 1, 0, 0, 0, 0, 0);
    G_spl<<<gSPL, 256, 0, stream>>>(
        ff1b, wD2T + (size_t)i * HF, nullptr, nullptr, scf, nullptr,
        S, H, F / 4, F, F, F / 4, 1.f, 1, 0, 0, 0, 0, SH);
    r4ln_k<<<dim3(S), 256, 0, stream>>>(scf, db2 + (size_t)i * H, y_f,
        dlnw + (size_t)(i * 3 + 2) * H, dlnb + (size_t)(i * 3 + 2) * H, y_f, y_b);
  }
  // final norm + feats + parallel viterbi
  ln_k<<<dim3(S), 256, 0, stream>>>(y_f, dnw, dnb, tmpf, memb);
  feats_k<<<dim3(S / 8), 256, 0, stream>>>(tmpf, h2tw, h2tb, ftsf);
  float* outF = (float*)d_out;
  vit_p1<<<dim3(VC), 256, 0, stream>>>(ftsf, trns, McB);
  vit_p2<<<dim3(1), 64, 0, stream>>>(McB, trns, bfvB, termB, outF);
  vit_p3<<<dim3(VC), 64, 0, stream>>>(ftsf, trns, bfvB, bpgB);
  vit_p4<<<dim3(1), VC, 0, stream>>>(bpgB, termB, outF);
}

// Round 5
// 1733.749 us; speedup vs baseline: 3.6388x; 1.0816x over previous
//
#include <hip/hip_runtime.h>
#include <cstdint>

#define SS 2048
#define HHd 512
#define FFd 2048
#define TTd 32
#define LLd 6
#define VW 16
#define VC 128

typedef float f32x4 __attribute__((ext_vector_type(4)));
typedef __bf16 bf16x8 __attribute__((ext_vector_type(8)));
typedef short short8v __attribute__((ext_vector_type(8)));
typedef short short4v __attribute__((ext_vector_type(4)));

__device__ __forceinline__ short f2b(float f) {
  unsigned u = __builtin_bit_cast(unsigned, f);
  u += 0x7fffu + ((u >> 16) & 1u);
  return (short)(u >> 16);
}

typedef const __attribute__((address_space(1))) void gv_t;
typedef __attribute__((address_space(3))) void lv_t;
__device__ __forceinline__ void gload16(const void* g, void* l) {
  __builtin_amdgcn_global_load_lds((gv_t*)g, (lv_t*)l, 16, 0, 0);
}

// ------------------------------ GEMM (all-TB, BK=64, swizzled LDS) ------------------------------
// C[M,N] = A[M,K] @ B^T, B is [N,K] row-major bf16.
// LDS rows = 64 shorts (128B, 8 16B-slots); phys slot = logical slot ^ (row&7).
// Staging: gload16 writes linearly; global source pre-swizzled: col16 = (l&7)^((l>>3)&7).
// z-batching: B += (z/zdiv)*bs1 + (z%zdiv)*bs2; bias likewise; C += z*cStr; k-offset = z*kzS (split-K).
template<int BMt, int BNt, bool BIAS, bool RELU, bool RESID, bool OUTF, bool OUTB>
__global__ __launch_bounds__(256) void gemm3(
    const short* __restrict__ A, const short* __restrict__ Bb,
    const float* __restrict__ biasb, const float* __restrict__ resid,
    float* __restrict__ Cfb, short* __restrict__ Cbb,
    int M, int N, int K, int lda, int ldb, int kzS, float scale,
    int zdiv, long bs1, long bs2, int bb1, int bb2, long cStr)
{
  constexpr int MR = BMt / 32, NR = BNt / 32;
  constexpr int WMt = BMt / 2, WNt = BNt / 2;
  constexpr int ACALLS = BMt / 8;
  constexpr int TOT = (BMt + BNt) / 8;
  constexpr int CPW = TOT / 4;

  const int z = blockIdx.z;
  const short* Bp = Bb + (long)(z / zdiv) * bs1 + (long)(z % zdiv) * bs2;
  const float* bias = BIAS ? (biasb + (z / zdiv) * bb1 + (z % zdiv) * bb2) : nullptr;
  const int kz = z * kzS;

  const int m0 = blockIdx.y * BMt;
  const int n0 = blockIdx.x * BNt;

  __shared__ __align__(16) short As[BMt * 64];
  __shared__ __align__(16) short Bs[BNt * 64];

  const int tid = threadIdx.x;
  const int lane = tid & 63;
  const int w = tid >> 6;

  const short* srcs[CPW];
  short* ldss[CPW];
  {
    const int rl8 = lane >> 3;
    const int c16 = (lane & 7) ^ rl8;
#pragma unroll
    for (int c = 0; c < CPW; ++c) {
      int q = w * CPW + c;
      if (q < ACALLS) {
        int row = q * 8 + rl8;
        srcs[c] = A + (long)(m0 + row) * lda + kz + c16 * 8;
        ldss[c] = &As[q * 512];
      } else {
        int row = (q - ACALLS) * 8 + rl8;
        srcs[c] = Bp + (long)(n0 + row) * ldb + kz + c16 * 8;
        ldss[c] = &Bs[(q - ACALLS) * 512];
      }
    }
  }

  const int lrow = lane & 15;
  const int slotb = lane >> 4;          // 0..3
  const int wm = (w >> 1) * WMt, wn = (w & 1) * WNt;

  f32x4 acc[MR][NR] = {};

  for (int k0 = 0; k0 < K; k0 += 64) {
#pragma unroll
    for (int c = 0; c < CPW; ++c) gload16(srcs[c], ldss[c]);
#pragma unroll
    for (int c = 0; c < CPW; ++c) srcs[c] += 64;
    __syncthreads();
#pragma unroll
    for (int s = 0; s < 2; ++s) {
      bf16x8 af[MR], bfv[NR];
#pragma unroll
      for (int f = 0; f < MR; ++f) {
        int row = wm + f * 16 + lrow;
        int phys = (slotb + s * 4) ^ (row & 7);
        af[f] = *(const bf16x8*)&As[row * 64 + phys * 8];
      }
#pragma unroll
      for (int f = 0; f < NR; ++f) {
        int row = wn + f * 16 + lrow;
        int phys = (slotb + s * 4) ^ (row & 7);
        bfv[f] = *(const bf16x8*)&Bs[row * 64 + phys * 8];
      }
#pragma unroll
      for (int i = 0; i < MR; ++i)
#pragma unroll
        for (int j = 0; j < NR; ++j)
          acc[i][j] = __builtin_amdgcn_mfma_f32_16x16x32_bf16(af[i], bfv[j], acc[i][j], 0, 0, 0);
    }
    __syncthreads();
  }

  float* Cf = OUTF ? (Cfb + (long)z * cStr) : nullptr;
  short* Cb = OUTB ? (Cbb + (long)z * cStr) : nullptr;
  const int crow = (lane >> 4) * 4;
  const int ccol = lane & 15;
#pragma unroll
  for (int i = 0; i < MR; ++i) {
#pragma unroll
    for (int j = 0; j < NR; ++j) {
      int gc = n0 + wn + j * 16 + ccol;
      float bv = BIAS ? bias[gc] : 0.f;
#pragma unroll
      for (int r = 0; r < 4; ++r) {
        int gr = m0 + wm + i * 16 + crow + r;
        long off = (long)gr * N + gc;
        float v = acc[i][j][r] * scale + bv;
        if (RESID) v += resid[off];
        if (RELU) v = v > 0.f ? v : 0.f;
        if (OUTF) Cf[off] = v;
        if (OUTB) Cb[off] = f2b(v);
      }
    }
  }
}

// ---------------- split-K=4 reduce -> bf16 ----------------
__global__ __launch_bounds__(256) void r4b_k(const float* __restrict__ pb, short* __restrict__ out) {
  const long SH = (long)SS * HHd;
  long i = ((long)blockIdx.x * 256 + threadIdx.x) * 4;
  f32x4 a = *(const f32x4*)(pb + i);
  f32x4 b = *(const f32x4*)(pb + SH + i);
  f32x4 c = *(const f32x4*)(pb + 2 * SH + i);
  f32x4 d = *(const f32x4*)(pb + 3 * SH + i);
  f32x4 s = (a + b) + (c + d);
  short4v o;
  o[0] = f2b(s[0]); o[1] = f2b(s[1]); o[2] = f2b(s[2]); o[3] = f2b(s[3]);
  *(short4v*)(out + i) = o;
}

// ---------------- split-K=4 reduce + bias + resid + LayerNorm ----------------
__global__ __launch_bounds__(256) void r4ln_k(const float* __restrict__ pb,
                                              const float* __restrict__ bias,
                                              const float* __restrict__ resid,
                                              const float* __restrict__ w, const float* __restrict__ b,
                                              float* __restrict__ Yf, short* __restrict__ Yb) {
  const long SH = (long)SS * HHd;
  const int row = blockIdx.x, tid = threadIdx.x;
  long base = (long)row * HHd;
  float x0 = bias[tid] + resid[base + tid];
  float x1 = bias[tid + 256] + resid[base + tid + 256];
#pragma unroll
  for (int sk = 0; sk < 4; ++sk) {
    x0 += pb[sk * SH + base + tid];
    x1 += pb[sk * SH + base + tid + 256];
  }
  float s = x0 + x1;
#pragma unroll
  for (int o = 32; o; o >>= 1) s += __shfl_xor(s, o);
  __shared__ float r1[4], r2[4];
  if ((tid & 63) == 0) r1[tid >> 6] = s;
  __syncthreads();
  float mean = (r1[0] + r1[1] + r1[2] + r1[3]) * (1.f / HHd);
  float d0 = x0 - mean, d1 = x1 - mean;
  float q = d0 * d0 + d1 * d1;
#pragma unroll
  for (int o = 32; o; o >>= 1) q += __shfl_xor(q, o);
  if ((tid & 63) == 0) r2[tid >> 6] = q;
  __syncthreads();
  float var = (r2[0] + r2[1] + r2[2] + r2[3]) * (1.f / HHd);
  float rs = rsqrtf(var + 1e-5f);
  float o0 = d0 * rs * w[tid] + b[tid];
  float o1 = d1 * rs * w[tid + 256] + b[tid + 256];
  Yf[base + tid] = o0; Yf[base + tid + 256] = o1;
  Yb[base + tid] = f2b(o0); Yb[base + tid + 256] = f2b(o1);
}

// ---------------- split-K=2 reduce + bias + resid + LayerNorm (out-proj fusion) ----------------
__global__ __launch_bounds__(256) void r2rln_k(const float* __restrict__ pb,
                                               const float* __restrict__ bias,
                                               const float* __restrict__ resid,
                                               const float* __restrict__ w, const float* __restrict__ b,
                                               float* __restrict__ Yf, short* __restrict__ Yb) {
  const long SH = (long)SS * HHd;
  const int row = blockIdx.x, tid = threadIdx.x;
  long base = (long)row * HHd;
  float x0 = pb[base + tid] + pb[SH + base + tid] + bias[tid] + resid[base + tid];
  float x1 = pb[base + tid + 256] + pb[SH + base + tid + 256] + bias[tid + 256] + resid[base + tid + 256];
  float s = x0 + x1;
#pragma unroll
  for (int o = 32; o; o >>= 1) s += __shfl_xor(s, o);
  __shared__ float r1[4], r2[4];
  if ((tid & 63) == 0) r1[tid >> 6] = s;
  __syncthreads();
  float mean = (r1[0] + r1[1] + r1[2] + r1[3]) * (1.f / HHd);
  float d0 = x0 - mean, d1 = x1 - mean;
  float q = d0 * d0 + d1 * d1;
#pragma unroll
  for (int o = 32; o; o >>= 1) q += __shfl_xor(q, o);
  if ((tid & 63) == 0) r2[tid >> 6] = q;
  __syncthreads();
  float var = (r2[0] + r2[1] + r2[2] + r2[3]) * (1.f / HHd);
  float rs = rsqrtf(var + 1e-5f);
  float o0 = d0 * rs * w[tid] + b[tid];
  float o1 = d1 * rs * w[tid + 256] + b[tid + 256];
  Yf[base + tid] = o0; Yf[base + tid + 256] = o1;
  Yb[base + tid] = f2b(o0); Yb[base + tid + 256] = f2b(o1);
}

// ---------------- f32 [K,N] -> bf16 [N,K] transpose-convert (batched z) ----------------
__global__ __launch_bounds__(256) void tconv_k(const float* __restrict__ in, short* __restrict__ out,
                                               int K, int N) {
  __shared__ float t[32][33];
  long zo = (long)blockIdx.z * K * N;
  int n0 = blockIdx.x * 32, k0 = blockIdx.y * 32;
  int tx = threadIdx.x & 31, ty = threadIdx.x >> 5;
#pragma unroll
  for (int i = 0; i < 4; ++i)
    t[ty + i * 8][tx] = in[zo + (long)(k0 + ty + i * 8) * N + n0 + tx];
  __syncthreads();
#pragma unroll
  for (int i = 0; i < 4; ++i)
    out[zo + (long)(n0 + ty + i * 8) * K + k0 + tx] = f2b(t[tx][ty + i * 8]);
}

// ---------------- bf16 [R,C] -> bf16 [C,R] transpose (batched z, separate strides) ----------------
__global__ __launch_bounds__(256) void tb16_k(const short* __restrict__ in, short* __restrict__ out,
                                              int R, int C, long inStride, long outStride) {
  __shared__ short t[32][34];
  const short* inp = in + (long)blockIdx.z * inStride;
  short* outp = out + (long)blockIdx.z * outStride;
  int c0 = blockIdx.x * 32, r0 = blockIdx.y * 32;
  int tx = threadIdx.x & 31, ty = threadIdx.x >> 5;
#pragma unroll
  for (int i = 0; i < 4; ++i)
    t[ty + i * 8][tx] = inp[(long)(r0 + ty + i * 8) * C + c0 + tx];
  __syncthreads();
#pragma unroll
  for (int i = 0; i < 4; ++i)
    outp[(long)(c0 + ty + i * 8) * R + r0 + tx] = t[tx][ty + i * 8];
}

// ------------------------------ softmax over rows of [SS,SS] ------------------------------
__global__ __launch_bounds__(256) void softmax_k(const float* __restrict__ Sc, short* __restrict__ P) {
  const int row = blockIdx.x;
  const float* src = Sc + (long)row * SS;
  const int tid = threadIdx.x;
  float vals[8];
  float mx = -3.0e38f;
#pragma unroll
  for (int i = 0; i < 8; ++i) {
    vals[i] = src[tid + i * 256];
    mx = fmaxf(mx, vals[i]);
  }
#pragma unroll
  for (int o = 32; o; o >>= 1) mx = fmaxf(mx, __shfl_xor(mx, o));
  __shared__ float r1[4], r2[4];
  if ((tid & 63) == 0) r1[tid >> 6] = mx;
  __syncthreads();
  mx = fmaxf(fmaxf(r1[0], r1[1]), fmaxf(r1[2], r1[3]));
  float sum = 0.f;
#pragma unroll
  for (int i = 0; i < 8; ++i) { vals[i] = __expf(vals[i] - mx); sum += vals[i]; }
#pragma unroll
  for (int o = 32; o; o >>= 1) sum += __shfl_xor(sum, o);
  if ((tid & 63) == 0) r2[tid >> 6] = sum;
  __syncthreads();
  sum = r2[0] + r2[1] + r2[2] + r2[3];
  float inv = 1.0f / sum;
  short* dst = P + (long)row * SS;
#pragma unroll
  for (int i = 0; i < 8; ++i) dst[tid + i * 256] = f2b(vals[i] * inv);
}

// ------------------------------ LayerNorm over rows of [SS,HHd] ------------------------------
__global__ __launch_bounds__(256) void ln_k(const float* __restrict__ X, const float* __restrict__ w,
                                            const float* __restrict__ b, float* __restrict__ Yf,
                                            short* __restrict__ Yb) {
  const int row = blockIdx.x;
  const int tid = threadIdx.x;
  const float* src = X + (long)row * HHd;
  float x0 = src[tid], x1 = src[tid + 256];
  float s = x0 + x1;
#pragma unroll
  for (int o = 32; o; o >>= 1) s += __shfl_xor(s, o);
  __shared__ float r1[4], r2[4];
  if ((tid & 63) == 0) r1[tid >> 6] = s;
  __syncthreads();
  float mean = (r1[0] + r1[1] + r1[2] + r1[3]) * (1.f / HHd);
  float d0 = x0 - mean, d1 = x1 - mean;
  float q = d0 * d0 + d1 * d1;
#pragma unroll
  for (int o = 32; o; o >>= 1) q += __shfl_xor(q, o);
  if ((tid & 63) == 0) r2[tid >> 6] = q;
  __syncthreads();
  float var = (r2[0] + r2[1] + r2[2] + r2[3]) * (1.f / HHd);
  float rs = rsqrtf(var + 1e-5f);
  float o0 = d0 * rs * w[tid] + b[tid];
  float o1 = d1 * rs * w[tid + 256] + b[tid + 256];
  long base = (long)row * HHd;
  Yf[base + tid] = o0; Yf[base + tid + 256] = o1;
  Yb[base + tid] = f2b(o0); Yb[base + tid + 256] = f2b(o1);
}

// ------------------------------ embedding gather ------------------------------
__global__ __launch_bounds__(256) void gather_k(const int* __restrict__ sent, const float* __restrict__ emb,
                                                float* __restrict__ hf, short* __restrict__ hb,
                                                float* __restrict__ yf, short* __restrict__ yb) {
  long i = (long)blockIdx.x * 256 + threadIdx.x;
  int s = (int)(i >> 9);
  int hcol = (int)(i & 511);
  float v = emb[(long)sent[s] * HHd + hcol];
  short bb = f2b(v);
  hf[i] = v; yf[i] = v; hb[i] = bb; yb[i] = bb;
}

// ------------------------------ feats: [SS,HHd] @ [HHd,TTd] + b (f32) ------------------------------
__global__ __launch_bounds__(256) void feats_k(const float* __restrict__ Y, const float* __restrict__ W,
                                               const float* __restrict__ b, float* __restrict__ feats) {
  __shared__ float ys[8 * HHd];
  const int row0 = blockIdx.x * 8;
  for (int i = threadIdx.x; i < 8 * HHd; i += 256) ys[i] = Y[(long)row0 * HHd + i];
  __syncthreads();
  const int n = threadIdx.x & 31, r = threadIdx.x >> 5;
  float acc = b[n];
  const float* yr = &ys[r * HHd];
  for (int k = 0; k < HHd; ++k) acc = fmaf(yr[k], W[k * TTd + n], acc);
  feats[(long)(row0 + r) * TTd + n] = acc;
}

// ============================== Parallel Viterbi (hierarchical max-plus scan) ==============================
// P1: fine chunk matrices Mf[VC] (VW steps each).
__global__ __launch_bounds__(256) void vit_p1(const float* __restrict__ feats,
                                              const float* __restrict__ trans,
                                              float* __restrict__ Mc) {
  __shared__ float trS[1024];
  __shared__ float fS[VW * 32];
  __shared__ float Ga[32 * 33], Gb[32 * 33];
  const int c = blockIdx.x, tid = threadIdx.x;
  for (int i = tid; i < 1024; i += 256) trS[i] = trans[i];
  for (int i = tid; i < VW * 32; i += 256) fS[i] = feats[c * VW * 32 + i];
  __syncthreads();
  for (int i = tid; i < 1024; i += 256) {
    int n = i >> 5, q = i & 31;
    Ga[n * 33 + q] = trS[i] + fS[n];
  }
  __syncthreads();
  float* G = Ga;
  float* Gn = Gb;
  const int q = tid & 31, nb = (tid >> 5) * 4;
  for (int s = 1; s < VW; ++s) {
    float m0 = -3.0e38f, m1 = -3.0e38f, m2 = -3.0e38f, m3 = -3.0e38f;
    for (int pp = 0; pp < 32; ++pp) {
      float g = G[pp * 33 + q];
      m0 = fmaxf(m0, trS[(nb + 0) * 32 + pp] + g);
      m1 = fmaxf(m1, trS[(nb + 1) * 32 + pp] + g);
      m2 = fmaxf(m2, trS[(nb + 2) * 32 + pp] + g);
      m3 = fmaxf(m3, trS[(nb + 3) * 32 + pp] + g);
    }
    Gn[(nb + 0) * 33 + q] = m0 + fS[s * 32 + nb + 0];
    Gn[(nb + 1) * 33 + q] = m1 + fS[s * 32 + nb + 1];
    Gn[(nb + 2) * 33 + q] = m2 + fS[s * 32 + nb + 2];
    Gn[(nb + 3) * 33 + q] = m3 + fS[s * 32 + nb + 3];
    __syncthreads();
    float* t = G; G = Gn; Gn = t;
  }
  for (int i = tid; i < 1024; i += 256) Mc[c * 1024 + i] = G[(i >> 5) * 33 + (i & 31)];
}

// P1b: compose 4 fine matrices -> 1 coarse matrix (VC/4 blocks).
__global__ __launch_bounds__(256) void vit_p1b(const float* __restrict__ Mf, float* __restrict__ Mcrs) {
  __shared__ float Ga[32 * 33], Gb[32 * 33], Ms[1024];
  const int c = blockIdx.x, tid = threadIdx.x;
  for (int i = tid; i < 1024; i += 256) Ga[(i >> 5) * 33 + (i & 31)] = Mf[(4 * c) * 1024 + i];
  float* G = Ga;
  float* Gn = Gb;
  const int q = tid & 31, nb = (tid >> 5) * 4;
  for (int j = 1; j < 4; ++j) {
    for (int i = tid; i < 1024; i += 256) Ms[i] = Mf[(4 * c + j) * 1024 + i];
    __syncthreads();
    float m0 = -3.0e38f, m1 = -3.0e38f, m2 = -3.0e38f, m3 = -3.0e38f;
    for (int pp = 0; pp < 32; ++pp) {
      float g = G[pp * 33 + q];
      m0 = fmaxf(m0, Ms[(nb + 0) * 32 + pp] + g);
      m1 = fmaxf(m1, Ms[(nb + 1) * 32 + pp] + g);
      m2 = fmaxf(m2, Ms[(nb + 2) * 32 + pp] + g);
      m3 = fmaxf(m3, Ms[(nb + 3) * 32 + pp] + g);
    }
    Gn[(nb + 0) * 33 + q] = m0;
    Gn[(nb + 1) * 33 + q] = m1;
    Gn[(nb + 2) * 33 + q] = m2;
    Gn[(nb + 3) * 33 + q] = m3;
    __syncthreads();
    float* t = G; G = Gn; Gn = t;
  }
  for (int i = tid; i < 1024; i += 256) Mcrs[c * 1024 + i] = G[(i >> 5) * 33 + (i & 31)];
}

__device__ __forceinline__ float vstep(float fv, int p0, const f32x4& M0, const f32x4& M1,
                                       const f32x4& M2, const f32x4& M3) {
  float mv[16];
#pragma unroll
  for (int j = 0; j < 4; ++j) { mv[j] = M0[j]; mv[4 + j] = M1[j]; mv[8 + j] = M2[j]; mv[12 + j] = M3[j]; }
  float cnd[16];
#pragma unroll
  for (int j = 0; j < 16; ++j) cnd[j] = __shfl(fv, p0 + j) + mv[j];
  float t8[8], t4[4];
#pragma unroll
  for (int j = 0; j < 8; ++j) t8[j] = fmaxf(cnd[2 * j], cnd[2 * j + 1]);
#pragma unroll
  for (int j = 0; j < 4; ++j) t4[j] = fmaxf(t8[2 * j], t8[2 * j + 1]);
  float bv = fmaxf(fmaxf(t4[0], t4[1]), fmaxf(t4[2], t4[3]));
  return fmaxf(bv, __shfl_xor(bv, 32));
}

// P2: serial scan over 32 coarse matrices (depth-2 prefetch, 3-buffer static rotation).
__global__ __launch_bounds__(64) void vit_p2(const float* __restrict__ Mcrs,
                                             const float* __restrict__ trans,
                                             float* __restrict__ bfvF,
                                             float* __restrict__ term,
                                             float* __restrict__ out) {
  const int lane = threadIdx.x, n = lane & 31, h = lane >> 5, p0 = h << 4;
  float fv = (n == 30) ? 0.f : -10000.f;
  if (lane < 32) bfvF[n] = fv;
  const float* base = Mcrs + n * 32 + p0;
  f32x4 A0, A1, A2, A3, B0, B1, B2, B3, C0, C1, C2, C3;
#define LDM(d0, d1, d2, d3, c) { const float* M = base + (c) * 1024; \
  d0 = *(const f32x4*)M; d1 = *(const f32x4*)(M + 4); d2 = *(const f32x4*)(M + 8); d3 = *(const f32x4*)(M + 12); }
  LDM(A0, A1, A2, A3, 0) LDM(B0, B1, B2, B3, 1) LDM(C0, C1, C2, C3, 2)
#pragma unroll 1
  for (int c = 0; c < 30; c += 3) {
    fv = vstep(fv, p0, A0, A1, A2, A3); if (lane < 32) bfvF[(4 * (c + 1)) * 32 + n] = fv;
    { int cl = (c + 3) & 31; LDM(A0, A1, A2, A3, cl) }
    fv = vstep(fv, p0, B0, B1, B2, B3); if (lane < 32) bfvF[(4 * (c + 2)) * 32 + n] = fv;
    { int cl = (c + 4) & 31; LDM(B0, B1, B2, B3, cl) }
    fv = vstep(fv, p0, C0, C1, C2, C3); if (lane < 32) bfvF[(4 * (c + 3)) * 32 + n] = fv;
    { int cl = (c + 5) & 31; LDM(C0, C1, C2, C3, cl) }
  }
  fv = vstep(fv, p0, A0, A1, A2, A3); if (lane < 32) bfvF[(4 * 31) * 32 + n] = fv;
  fv = vstep(fv, p0, B0, B1, B2, B3); if (lane < 32) bfvF[(4 * 32) * 32 + n] = fv;
#undef LDM
  float v = fv + trans[31 * 32 + n];
  int idx = n;
#pragma unroll
  for (int o = 16; o; o >>= 1) {
    float ov = __shfl_xor(v, o);
    int oi = __shfl_xor(idx, o);
    if (ov > v || (ov == v && oi < idx)) { v = ov; idx = oi; }
  }
  if (lane == 0) { out[0] = v; term[0] = (float)idx; }
}

// P2b: expand coarse boundaries to fine boundaries (VC/4 blocks x 1 wave, depth 3).
__global__ __launch_bounds__(64) void vit_p2b(const float* __restrict__ Mf, float* __restrict__ bfvF) {
  const int c = blockIdx.x, lane = threadIdx.x, n = lane & 31, h = lane >> 5, p0 = h << 4;
  float fv = bfvF[(4 * c) * 32 + n];
  const float* base = Mf + (size_t)(4 * c) * 1024 + n * 32 + p0;
#pragma unroll
  for (int j = 0; j < 3; ++j) {
    const float* M = base + j * 1024;
    f32x4 A0 = *(const f32x4*)M, A1 = *(const f32x4*)(M + 4);
    f32x4 A2 = *(const f32x4*)(M + 8), A3 = *(const f32x4*)(M + 12);
    fv = vstep(fv, p0, A0, A1, A2, A3);
    if (lane < 32) bfvF[(4 * c + j + 1) * 32 + n] = fv;
  }
}

// P3: per-chunk forward re-run producing backpointers (VC waves, parallel).
__global__ __launch_bounds__(64) void vit_p3(const float* __restrict__ feats,
                                             const float* __restrict__ trans,
                                             const float* __restrict__ bfvF,
                                             unsigned char* __restrict__ bp) {
  const int c = blockIdx.x, lane = threadIdx.x, n = lane & 31, h = lane >> 5, p0 = h << 4;
  float tr[16];
#pragma unroll
  for (int j = 0; j < 16; ++j) tr[j] = trans[n * 32 + p0 + j];
  float fv = bfvF[c * 32 + n];
  float ft[VW];
  for (int s = 0; s < VW; ++s) ft[s] = feats[(c * VW + s) * 32 + n];
  for (int s = 0; s < VW; ++s) {
    float cd[16];
#pragma unroll
    for (int j = 0; j < 16; ++j) cd[j] = __shfl(fv, p0 + j) + tr[j];
    float v8[8]; int i8a[8];
#pragma unroll
    for (int j = 0; j < 8; ++j) {
      bool g = cd[2 * j + 1] > cd[2 * j];
      v8[j] = g ? cd[2 * j + 1] : cd[2 * j];
      i8a[j] = g ? 2 * j + 1 : 2 * j;
    }
    float v4[4]; int i4a[4];
#pragma unroll
    for (int j = 0; j < 4; ++j) {
      bool g = v8[2 * j + 1] > v8[2 * j];
      v4[j] = g ? v8[2 * j + 1] : v8[2 * j];
      i4a[j] = g ? i8a[2 * j + 1] : i8a[2 * j];
    }
    float v2[2]; int i2a[2];
#pragma unroll
    for (int j = 0; j < 2; ++j) {
      bool g = v4[2 * j + 1] > v4[2 * j];
      v2[j] = g ? v4[2 * j + 1] : v4[2 * j];
      i2a[j] = g ? i4a[2 * j + 1] : i4a[2 * j];
    }
    bool g1 = v2[1] > v2[0];
    float bv = g1 ? v2[1] : v2[0];
    int bi = p0 + (g1 ? i2a[1] : i2a[0]);
    float ov = __shfl_xor(bv, 32);
    int oi = __shfl_xor(bi, 32);
    bool takeo = h ? (ov >= bv) : (ov > bv);
    float m = takeo ? ov : bv;
    int mi = takeo ? oi : bi;
    if (!h) bp[(c * VW + s) * 32 + n] = (unsigned char)mi;
    fv = m + ft[s];
  }
}

// P4: backtrack via chunk map composition (1 block, VC threads).
__global__ __launch_bounds__(VC) void vit_p4(const unsigned char* __restrict__ bp,
                                             const float* __restrict__ term,
                                             float* __restrict__ out) {
  __shared__ unsigned char GsL[VC * 32];
  __shared__ unsigned char bnd[VC];
  const int lane = threadIdx.x;  // chunk id, 0..VC-1
  unsigned char g[32];
#pragma unroll
  for (int j = 0; j < 32; ++j) g[j] = (unsigned char)j;
  for (int s = VW - 1; s >= 0; --s) {
    const unsigned char* rowp = bp + (lane * VW + s) * 32;
#pragma unroll
    for (int j = 0; j < 32; ++j) g[j] = rowp[g[j]];
  }
#pragma unroll
  for (int j = 0; j < 32; ++j) GsL[lane * 32 + j] = g[j];
  __syncthreads();
  if (lane == 0) {
    bnd[VC - 1] = (unsigned char)(int)term[0];
    for (int cc = VC - 1; cc >= 1; --cc) bnd[cc - 1] = GsL[cc * 32 + bnd[cc]];
  }
  __syncthreads();
  int x = bnd[lane];
  out[1 + lane * VW + VW - 1] = (float)x;
  for (int k = VW - 2; k >= 0; --k) {
    x = bp[(lane * VW + k + 1) * 32 + x];
    out[1 + lane * VW + k] = (float)x;
  }
}

// ------------------------------ host ------------------------------
extern "C" void kernel_launch(void* const* d_in, const int* in_sizes, int n_in,
                              void* d_out, int out_size, void* d_ws, size_t ws_size,
                              hipStream_t stream) {
  (void)in_sizes; (void)n_in; (void)out_size; (void)ws_size;
  const int H = HHd, F = FFd, S = SS, L = LLd;
  const long HH2 = (long)H * H;
  const long SH = (long)S * H;
  const long HF = (long)H * F;

  const int*   sent = (const int*)d_in[0];
  const float* embd = (const float*)d_in[1];
  const float* eaw  = (const float*)d_in[2];
  const float* eab  = (const float*)d_in[3];
  const float* ew1  = (const float*)d_in[4];
  const float* eb1  = (const float*)d_in[5];
  const float* ew2  = (const float*)d_in[6];
  const float* eb2  = (const float*)d_in[7];
  const float* elnw = (const float*)d_in[8];
  const float* elnb = (const float*)d_in[9];
  const float* daw  = (const float*)d_in[10];
  const float* dab  = (const float*)d_in[11];
  const float* dw1  = (const float*)d_in[12];
  const float* db1  = (const float*)d_in[13];
  const float* dw2  = (const float*)d_in[14];
  const float* db2  = (const float*)d_in[15];
  const float* dlnw = (const float*)d_in[16];
  const float* dlnb = (const float*)d_in[17];
  const float* enw  = (const float*)d_in[18];
  const float* enb  = (const float*)d_in[19];
  const float* dnw  = (const float*)d_in[20];
  const float* dnb  = (const float*)d_in[21];
  const float* h2tw = (const float*)d_in[22];
  const float* h2tb = (const float*)d_in[23];
  const float* trns = (const float*)d_in[24];

  char* p = (char*)d_ws;
  auto alloc = [&](size_t bytes) -> char* {
    char* r = p;
    p += (bytes + 255) & ~(size_t)255;
    return r;
  };
  short* wEAT = (short*)alloc((size_t)L * 4 * HH2 * 2);
  short* wDAT = (short*)alloc((size_t)L * 8 * HH2 * 2);
  short* wE1T = (short*)alloc((size_t)L * HF * 2);
  short* wE2T = (short*)alloc((size_t)L * HF * 2);
  short* wD1T = (short*)alloc((size_t)L * HF * 2);
  short* wD2T = (short*)alloc((size_t)L * HF * 2);
  float* h_f  = (float*)alloc(SH * 4);
  short* h_b  = (short*)alloc(SH * 2);
  float* y_f  = (float*)alloc(SH * 4);
  short* y_b  = (short*)alloc(SH * 2);
  float* tmpf = (float*)alloc(SH * 4);
  short* qkvb = (short*)alloc(3 * SH * 2);
  float* scf  = (float*)alloc((size_t)S * S * 4);   // scores AND split-K partial buffer (16MB)
  short* P_b  = (short*)alloc((size_t)S * S * 2);
  short* attb = (short*)alloc(SH * 2);
  short* ff1b = (short*)alloc((size_t)S * F * 2);
  short* memb = (short*)alloc(SH * 2);
  short* ckvA = (short*)alloc((size_t)2 * L * SH * 2);  // interleaved cross K/V per layer
  short* cvT  = (short*)alloc((size_t)L * SH * 2);
  float* ftsf = (float*)alloc((size_t)S * TTd * 4);
  float* McB  = (float*)alloc((size_t)VC * 1024 * 4);
  float* McrsB= (float*)alloc((size_t)(VC / 4) * 1024 * 4);
  float* bfvF = (float*)alloc((size_t)(VC + 1) * 32 * 4);
  float* termB= (float*)alloc(64);
  unsigned char* bpgB = (unsigned char*)alloc((size_t)2048 * 32);

  short* vtb = ff1b;           // V^T scratch aliases ff1b (disjoint lifetimes)

  const int ZBIG = 1 << 20;
  const float RSQ = 0.04419417382415922f;  // 1/sqrt(512)

  tconv_k<<<dim3(16, 16, L * 4), 256, 0, stream>>>(eaw, wEAT, H, H);
  tconv_k<<<dim3(16, 16, L * 8), 256, 0, stream>>>(daw, wDAT, H, H);
  tconv_k<<<dim3(64, 16, L), 256, 0, stream>>>(ew1, wE1T, H, F);
  tconv_k<<<dim3(16, 64, L), 256, 0, stream>>>(ew2, wE2T, F, H);
  tconv_k<<<dim3(64, 16, L), 256, 0, stream>>>(dw1, wD1T, H, F);
  tconv_k<<<dim3(16, 64, L), 256, 0, stream>>>(dw2, wD2T, F, H);

  gather_k<<<dim3((unsigned)(SH / 256)), 256, 0, stream>>>(sent, embd, h_f, h_b, y_f, y_b);

  // gemm variants (128x64 tiles -> 2 WG/CU occupancy; 64x64 where noted)
  auto G_qkv = gemm3<128, 64, true, false, false, false, true>;   // batched proj -> bf16
  auto G_q1  = gemm3<64, 64, true, false, false, false, true>;    // single proj -> bf16
  auto G_sc  = gemm3<128, 64, false, false, false, true, false>;  // scores / split-K partials -> f32
  auto G_s2  = gemm3<64, 64, false, false, false, true, false>;   // out-proj split-K2 partials -> f32
  auto G_ff1 = gemm3<128, 64, true, true, false, false, true>;    // bias+relu -> bf16

  dim3 gQKV(8, 16, 3), gSC(32, 16, 1), gSPL(8, 16, 4), gS2(8, 32, 2), gFF1(32, 16, 1), gQ1(8, 32, 1);

  // ---------------- encoder ----------------
  for (int i = 0; i < L; ++i) {
    G_qkv<<<gQKV, 256, 0, stream>>>(
        h_b, wEAT + (size_t)i * 4 * HH2, eab + (size_t)i * 4 * H, nullptr, nullptr, qkvb,
        S, H, H, H, H, 0, 1.f, ZBIG, 0, HH2, 0, H, SH);
    tb16_k<<<dim3(16, 64, 1), 256, 0, stream>>>(qkvb + 2 * SH, vtb, S, H, 0, 0);
    G_sc<<<gSC, 256, 0, stream>>>(
        qkvb, qkvb + SH, nullptr, nullptr, scf, nullptr,
        S, S, H, H, H, 0, RSQ, 1, 0, 0, 0, 0, 0);
    softmax_k<<<dim3(S), 256, 0, stream>>>(scf, P_b);
    G_sc<<<gSPL, 256, 0, stream>>>(
        P_b, vtb, nullptr, nullptr, scf, nullptr,
        S, H, S / 4, S, S, S / 4, 1.f, 1, 0, 0, 0, 0, SH);
    r4b_k<<<dim3(1024), 256, 0, stream>>>(scf, attb);
    G_s2<<<gS2, 256, 0, stream>>>(
        attb, wEAT + ((size_t)i * 4 + 3) * HH2, nullptr, nullptr, scf, nullptr,
        S, H, H / 2, H, H, H / 2, 1.f, 1, 0, 0, 0, 0, SH);
    r2rln_k<<<dim3(S), 256, 0, stream>>>(scf, eab + ((size_t)i * 4 + 3) * H, h_f,
        elnw + (size_t)(i * 2) * H, elnb + (size_t)(i * 2) * H, h_f, h_b);
    G_ff1<<<gFF1, 256, 0, stream>>>(
        h_b, wE1T + (size_t)i * HF, eb1 + (size_t)i * F, nullptr, nullptr, ff1b,
        S, F, H, H, H, 0, 1.f, 1, 0, 0, 0, 0, 0);
    G_sc<<<gSPL, 256, 0, stream>>>(
        ff1b, wE2T + (size_t)i * HF, nullptr, nullptr, scf, nullptr,
        S, H, F / 4, F, F, F / 4, 1.f, 1, 0, 0, 0, 0, SH);
    r4ln_k<<<dim3(S), 256, 0, stream>>>(scf, eb2 + (size_t)i * H, h_f,
        elnw + (size_t)(i * 2 + 1) * H, elnb + (size_t)(i * 2 + 1) * H, h_f, h_b);
  }
  ln_k<<<dim3(S), 256, 0, stream>>>(h_f, enw, enb, tmpf, memb);

  // cross K (j=5) and V (j=6) for all layers in one dispatch: z=2*layer + {0:K,1:V}
  G_qkv<<<dim3(8, 16, 2 * L), 256, 0, stream>>>(
      memb, wDAT + 5 * HH2, dab + 5 * H, nullptr, nullptr, ckvA,
      S, H, H, H, H, 0, 1.f, 2, 8 * HH2, HH2, 8 * H, H, SH);
  tb16_k<<<dim3(16, 64, L), 256, 0, stream>>>(ckvA + SH, cvT, S, H, 2 * SH, SH);

  // ---------------- decoder ----------------
  for (int i = 0; i < L; ++i) {
    G_qkv<<<gQKV, 256, 0, stream>>>(
        y_b, wDAT + (size_t)i * 8 * HH2, dab + (size_t)i * 8 * H, nullptr, nullptr, qkvb,
        S, H, H, H, H, 0, 1.f, ZBIG, 0, HH2, 0, H, SH);
    tb16_k<<<dim3(16, 64, 1), 256, 0, stream>>>(qkvb + 2 * SH, vtb, S, H, 0, 0);
    G_sc<<<gSC, 256, 0, stream>>>(
        qkvb, qkvb + SH, nullptr, nullptr, scf, nullptr,
        S, S, H, H, H, 0, RSQ, 1, 0, 0, 0, 0, 0);
    softmax_k<<<dim3(S), 256, 0, stream>>>(scf, P_b);
    G_sc<<<gSPL, 256, 0, stream>>>(
        P_b, vtb, nullptr, nullptr, scf, nullptr,
        S, H, S / 4, S, S, S / 4, 1.f, 1, 0, 0, 0, 0, SH);
    r4b_k<<<dim3(1024), 256, 0, stream>>>(scf, attb);
    G_s2<<<gS2, 256, 0, stream>>>(
        attb, wDAT + ((size_t)i * 8 + 3) * HH2, nullptr, nullptr, scf, nullptr,
        S, H, H / 2, H, H, H / 2, 1.f, 1, 0, 0, 0, 0, SH);
    r2rln_k<<<dim3(S), 256, 0, stream>>>(scf, dab + ((size_t)i * 8 + 3) * H, y_f,
        dlnw + (size_t)(i * 3) * H, dlnb + (size_t)(i * 3) * H, y_f, y_b);
    // cross-attn
    G_q1<<<gQ1, 256, 0, stream>>>(
        y_b, wDAT + ((size_t)i * 8 + 4) * HH2, dab + ((size_t)i * 8 + 4) * H, nullptr, nullptr, qkvb,
        S, H, H, H, H, 0, 1.f, ZBIG, 0, 0, 0, 0, 0);
    G_sc<<<gSC, 256, 0, stream>>>(
        qkvb, ckvA + (size_t)(2 * i) * SH, nullptr, nullptr, scf, nullptr,
        S, S, H, H, H, 0, RSQ, 1, 0, 0, 0, 0, 0);
    softmax_k<<<dim3(S), 256, 0, stream>>>(scf, P_b);
    G_sc<<<gSPL, 256, 0, stream>>>(
        P_b, cvT + (size_t)i * SH, nullptr, nullptr, scf, nullptr,
        S, H, S / 4, S, S, S / 4, 1.f, 1, 0, 0, 0, 0, SH);
    r4b_k<<<dim3(1024), 256, 0, stream>>>(scf, attb);
    G_s2<<<gS2, 256, 0, stream>>>(
        attb, wDAT + ((size_t)i * 8 + 7) * HH2, nullptr, nullptr, scf, nullptr,
        S, H, H / 2, H, H, H / 2, 1.f, 1, 0, 0, 0, 0, SH);
    r2rln_k<<<dim3(S), 256, 0, stream>>>(scf, dab + ((size_t)i * 8 + 7) * H, y_f,
        dlnw + (size_t)(i * 3 + 1) * H, dlnb + (size_t)(i * 3 + 1) * H, y_f, y_b);
    // FFN
    G_ff1<<<gFF1, 256, 0, stream>>>(
        y_b, wD1T + (size_t)i * HF, db1 + (size_t)i * F, nullptr, nullptr, ff1b,
        S, F, H, H, H, 0, 1.f, 1, 0, 0, 0, 0, 0);
    G_sc<<<gSPL, 256, 0, stream>>>(
        ff1b, wD2T + (size_t)i * HF, nullptr, nullptr, scf, nullptr,
        S, H, F / 4, F, F, F / 4, 1.f, 1, 0, 0, 0, 0, SH);
    r4ln_k<<<dim3(S), 256, 0, stream>>>(scf, db2 + (size_t)i * H, y_f,
        dlnw + (size_t)(i * 3 + 2) * H, dlnb + (size_t)(i * 3 + 2) * H, y_f, y_b);
  }
  // final norm + feats + hierarchical parallel viterbi
  ln_k<<<dim3(S), 256, 0, stream>>>(y_f, dnw, dnb, tmpf, memb);
  feats_k<<<dim3(S / 8), 256, 0, stream>>>(tmpf, h2tw, h2tb, ftsf);
  float* outF = (float*)d_out;
  vit_p1<<<dim3(VC), 256, 0, stream>>>(ftsf, trns, McB);
  vit_p1b<<<dim3(VC / 4), 256, 0, stream>>>(McB, McrsB);
  vit_p2<<<dim3(1), 64, 0, stream>>>(McrsB, trns, bfvF, termB, outF);
  vit_p2b<<<dim3(VC / 4), 64, 0, stream>>>(McB, bfvF);
  vit_p3<<<dim3(VC), 64, 0, stream>>>(ftsf, trns, bfvF, bpgB);
  vit_p4<<<dim3(1), VC, 0, stream>>>(bpgB, termB, outF);
}